// Round 1
// baseline (1504.830 us; speedup 1.0000x reference)
//
#include <hip/hip_runtime.h>
#include <hip/hip_bf16.h>

// ---------------------------------------------------------------------------
// GCN 2-layer forward:
//   dinv = rsqrt(indeg+1)
//   h  = x @ W1                      (f32 compute, bf16 store)
//   a1 = scatter_add(norm * h[src]) + dinv^2*h + b1 ; r = relu(a1)  (bf16)
//   h2 = r @ W2                      (bf16 in, f32 compute, bf16 store)
//   a2 = scatter_add(norm * h2[src]) + dinv^2*h2 + b2
//   out = log_softmax(a2, axis=1)    (64 cols == one wave)
// ---------------------------------------------------------------------------

__device__ inline float to_f32(float v) { return v; }
__device__ inline float to_f32(__hip_bfloat16 v) { return __bfloat162float(v); }

// ---------------- degree / dinv ----------------
__global__ __launch_bounds__(256) void deg_init(float* deg, int N) {
    int i = blockIdx.x * 256 + threadIdx.x;
    if (i < N) deg[i] = 1.0f;   // self-loop
}

__global__ __launch_bounds__(256) void deg_edges(const int* __restrict__ dst, float* deg, int E) {
    int e = blockIdx.x * 256 + threadIdx.x;
    if (e < E) atomicAdd(&deg[dst[e]], 1.0f);
}

__global__ __launch_bounds__(256) void deg_to_dinv(float* deg, int N) {
    int i = blockIdx.x * 256 + threadIdx.x;
    if (i < N) deg[i] = rsqrtf(deg[i]);   // deg >= 1 always (self-loop)
}

// ---------------- tiled f32 GEMM, C stored bf16 ----------------
#define BM 64
#define BN 64
#define BK 16

template<typename AT>
__global__ __launch_bounds__(256) void gemm_tiled(const AT* __restrict__ A,
                                                  const float* __restrict__ B,
                                                  __hip_bfloat16* __restrict__ C,
                                                  int M, int N, int K) {
    __shared__ float As[BK][BM + 1];
    __shared__ float Bs[BK][BN + 1];
    const int tid  = threadIdx.x;
    const int tx   = tid & 15;        // col group 0..15
    const int ty   = tid >> 4;        // row group 0..15
    const int arow = tid >> 2;        // 0..63
    const int akb  = (tid & 3) * 4;   // 0,4,8,12
    const int brow = tid >> 4;        // 0..15
    const int bcol = (tid & 15) * 4;  // 0..60

    const int row0 = blockIdx.x * BM;
    const int col0 = blockIdx.y * BN;

    float acc[4][4] = {};
    const int nk = K / BK;            // K is a multiple of 16 here (512, 128)
    for (int kt = 0; kt < nk; ++kt) {
        int garow = row0 + arow;
        if (garow < M) {
            const AT* ap = A + (size_t)garow * K + kt * BK + akb;
            #pragma unroll
            for (int i = 0; i < 4; ++i) As[akb + i][arow] = to_f32(ap[i]);
        } else {
            #pragma unroll
            for (int i = 0; i < 4; ++i) As[akb + i][arow] = 0.0f;
        }
        const float* bp = B + (size_t)(kt * BK + brow) * N + col0 + bcol;
        #pragma unroll
        for (int j = 0; j < 4; ++j) Bs[brow][bcol + j] = bp[j];
        __syncthreads();
        #pragma unroll
        for (int k = 0; k < BK; ++k) {
            float a[4], b[4];
            #pragma unroll
            for (int i = 0; i < 4; ++i) a[i] = As[k][ty * 4 + i];
            #pragma unroll
            for (int j = 0; j < 4; ++j) b[j] = Bs[k][tx * 4 + j];
            #pragma unroll
            for (int i = 0; i < 4; ++i)
                #pragma unroll
                for (int j = 0; j < 4; ++j)
                    acc[i][j] += a[i] * b[j];
        }
        __syncthreads();
    }
    #pragma unroll
    for (int i = 0; i < 4; ++i) {
        int row = row0 + ty * 4 + i;
        if (row >= M) continue;
        #pragma unroll
        for (int j = 0; j < 4; ++j) {
            int col = col0 + tx * 4 + j;
            C[(size_t)row * N + col] = __float2bfloat16(acc[i][j]);
        }
    }
}

// ---------------- edge scatter-add (atomic) ----------------
template<int F>
__global__ __launch_bounds__(256) void agg_edges(const int* __restrict__ src,
                                                 const int* __restrict__ dst,
                                                 const float* __restrict__ dinv,
                                                 const __hip_bfloat16* __restrict__ h,
                                                 float* __restrict__ agg, int E) {
    int t = blockIdx.x * 256 + threadIdx.x;
    int e = t / F;
    if (e >= E) return;
    int f = t - e * F;
    int s = src[e];
    int d = dst[e];
    float norm = dinv[s] * dinv[d];
    float v = __bfloat162float(h[(size_t)s * F + f]);
    atomicAdd(&agg[(size_t)d * F + f], v * norm);
}

// ---------------- bias + self-loop + relu, store bf16 (in-place over h) ----
__global__ __launch_bounds__(256) void bias_relu(const float* __restrict__ agg,
                                                 const __hip_bfloat16* h,
                                                 const float* __restrict__ dinv,
                                                 const float* __restrict__ b1,
                                                 __hip_bfloat16* r, int N) {
    int t = blockIdx.x * 256 + threadIdx.x;
    if (t >= N * 128) return;
    int n = t >> 7;
    int f = t & 127;
    float di = dinv[n];
    float v = agg[t] + di * di * __bfloat162float(h[t]) + b1[f];
    r[t] = __float2bfloat16(fmaxf(v, 0.0f));
}

// ---------------- bias + self-loop + log_softmax (64 cols = 1 wave) --------
__global__ __launch_bounds__(256) void final_lsm(float* out,
                                                 const __hip_bfloat16* __restrict__ h2,
                                                 const float* __restrict__ dinv,
                                                 const float* __restrict__ b2, int N) {
    int n = blockIdx.x * 4 + (threadIdx.x >> 6);
    int c = threadIdx.x & 63;
    if (n >= N) return;
    float di = dinv[n];
    size_t idx = (size_t)n * 64 + c;
    float v = out[idx] + di * di * __bfloat162float(h2[idx]) + b2[c];
    float m = v;
    #pragma unroll
    for (int o = 32; o > 0; o >>= 1) m = fmaxf(m, __shfl_xor(m, o));
    float s = expf(v - m);
    #pragma unroll
    for (int o = 32; o > 0; o >>= 1) s += __shfl_xor(s, o);
    out[idx] = v - m - logf(s);
}

// ---------------------------------------------------------------------------
extern "C" void kernel_launch(void* const* d_in, const int* in_sizes, int n_in,
                              void* d_out, int out_size, void* d_ws, size_t ws_size,
                              hipStream_t stream) {
    const float* x  = (const float*)d_in[0];
    const int*   ei = (const int*)d_in[1];
    const float* W1 = (const float*)d_in[2];
    const float* b1 = (const float*)d_in[3];
    const float* W2 = (const float*)d_in[4];
    const float* b2 = (const float*)d_in[5];
    float* out = (float*)d_out;

    const int N = in_sizes[0] / 512;   // 100000
    const int E = in_sizes[1] / 2;     // 1600000
    const int* src = ei;
    const int* dst = ei + E;

    // workspace layout
    char* ws = (char*)d_ws;
    size_t o = 0;
    auto take = [&](size_t bytes) { char* p = ws + o; o = (o + bytes + 255) & ~(size_t)255; return p; };
    float*          dinv = (float*)take((size_t)N * 4);
    __hip_bfloat16* h    = (__hip_bfloat16*)take((size_t)N * 128 * 2);  // also r (in-place)
    float*          agg1 = (float*)take((size_t)N * 128 * 4);           // also h2 region
    __hip_bfloat16* h2   = (__hip_bfloat16*)agg1;                       // reuse after relu

    // zero the accumulators (harness does not re-zero between replays)
    hipMemsetAsync(agg1, 0, (size_t)N * 128 * 4, stream);
    hipMemsetAsync(out, 0, (size_t)N * 64 * 4, stream);

    // degree -> dinv
    deg_init<<<(N + 255) / 256, 256, 0, stream>>>(dinv, N);
    deg_edges<<<(E + 255) / 256, 256, 0, stream>>>(dst, dinv, E);
    deg_to_dinv<<<(N + 255) / 256, 256, 0, stream>>>(dinv, N);

    // layer 1
    gemm_tiled<float><<<dim3((N + BM - 1) / BM, 128 / BN), 256, 0, stream>>>(x, W1, h, N, 128, 512);
    agg_edges<128><<<(size_t)E * 128 / 256, 256, 0, stream>>>(src, dst, dinv, h, agg1, E);
    bias_relu<<<(N * 128 + 255) / 256, 256, 0, stream>>>(agg1, h, dinv, b1, h, N);

    // layer 2
    gemm_tiled<__hip_bfloat16><<<dim3((N + BM - 1) / BM, 1), 256, 0, stream>>>(h, W2, h2, N, 64, 128);
    agg_edges<64><<<(size_t)E * 64 / 256, 256, 0, stream>>>(src, dst, dinv, h2, out, E);
    final_lsm<<<(N + 3) / 4, 256, 0, stream>>>(out, h2, dinv, b2, N);
}

// Round 2
// 822.097 us; speedup vs baseline: 1.8305x; 1.8305x over previous
//
#include <hip/hip_runtime.h>
#include <hip/hip_bf16.h>

// ---------------------------------------------------------------------------
// GCN 2-layer forward, CSR-gather aggregation (no feature atomics):
//   cnt  = in-degree (atomic int count)
//   row_start = exclusive_scan(cnt); cursor = row_start; dinv = rsqrt(cnt+1)
//   srcs[pos] = counting-sort of src by dst
//   h  = x @ W1                              (f32 compute, bf16 store)
//   r  = relu(gather_sum + dinv^2*h + b1)    (per-node wave, bf16 store)
//   h2 = r @ W2                              (bf16 in, f32 compute, bf16 store)
//   out = log_softmax(gather_sum + dinv^2*h2 + b2)   (64 cols == one wave)
// ---------------------------------------------------------------------------

__device__ inline float to_f32(float v) { return v; }
__device__ inline float to_f32(__hip_bfloat16 v) { return __bfloat162float(v); }

__device__ inline float bf16_lo(unsigned int p) {
    unsigned int u = (p & 0xffffu) << 16;
    return __uint_as_float(u);
}
__device__ inline float bf16_hi(unsigned int p) {
    unsigned int u = p & 0xffff0000u;
    return __uint_as_float(u);
}
__device__ inline unsigned int pack_bf16(float a, float b) {
    __hip_bfloat16 x = __float2bfloat16(a);
    __hip_bfloat16 y = __float2bfloat16(b);
    unsigned short xs = *reinterpret_cast<unsigned short*>(&x);
    unsigned short ys = *reinterpret_cast<unsigned short*>(&y);
    return (unsigned int)xs | ((unsigned int)ys << 16);
}

// ---------------- CSR build ----------------
__global__ __launch_bounds__(256) void count_deg(const int* __restrict__ dst, int* __restrict__ cnt, int E) {
    int e = blockIdx.x * 256 + threadIdx.x;
    if (e < E) atomicAdd(&cnt[dst[e]], 1);
}

__global__ __launch_bounds__(256) void scan_block_sums(const int* __restrict__ cnt, int* __restrict__ bsum, int N) {
    __shared__ int s[256];
    int i = blockIdx.x * 256 + threadIdx.x;
    s[threadIdx.x] = (i < N) ? cnt[i] : 0;
    __syncthreads();
    for (int off = 128; off > 0; off >>= 1) {
        if (threadIdx.x < off) s[threadIdx.x] += s[threadIdx.x + off];
        __syncthreads();
    }
    if (threadIdx.x == 0) bsum[blockIdx.x] = s[0];
}

// exclusive scan of block sums (nb <= 1024), one block
__global__ __launch_bounds__(1024) void scan_bsums(int* bsum, int nb) {
    __shared__ int s[1024];
    int v = (threadIdx.x < nb) ? bsum[threadIdx.x] : 0;
    s[threadIdx.x] = v;
    __syncthreads();
    for (int off = 1; off < 1024; off <<= 1) {
        int t = (threadIdx.x >= off) ? s[threadIdx.x - off] : 0;
        __syncthreads();
        s[threadIdx.x] += t;
        __syncthreads();
    }
    if (threadIdx.x < nb) bsum[threadIdx.x] = s[threadIdx.x] - v;  // exclusive
}

__global__ __launch_bounds__(256) void scan_final(const int* __restrict__ cnt, const int* __restrict__ bsum,
                                                  int* __restrict__ row_start, int* __restrict__ cursor,
                                                  float* __restrict__ dinv, int N) {
    __shared__ int s[256];
    int i = blockIdx.x * 256 + threadIdx.x;
    int v = (i < N) ? cnt[i] : 0;
    s[threadIdx.x] = v;
    __syncthreads();
    for (int off = 1; off < 256; off <<= 1) {
        int t = (threadIdx.x >= off) ? s[threadIdx.x - off] : 0;
        __syncthreads();
        s[threadIdx.x] += t;
        __syncthreads();
    }
    if (i < N) {
        int excl = s[threadIdx.x] - v + bsum[blockIdx.x];
        row_start[i] = excl;
        cursor[i]    = excl;
        dinv[i]      = rsqrtf((float)(v + 1));  // +1 self-loop
    }
}

__global__ __launch_bounds__(256) void scatter_edges(const int* __restrict__ src, const int* __restrict__ dst,
                                                     int* __restrict__ cursor, int* __restrict__ srcs, int E) {
    int e = blockIdx.x * 256 + threadIdx.x;
    if (e < E) {
        int pos = atomicAdd(&cursor[dst[e]], 1);
        srcs[pos] = src[e];
    }
}

// ---------------- tiled f32 GEMM, C stored bf16 ----------------
#define BM 64
#define BN 64
#define BK 16

template<typename AT>
__global__ __launch_bounds__(256) void gemm_tiled(const AT* __restrict__ A,
                                                  const float* __restrict__ B,
                                                  __hip_bfloat16* __restrict__ C,
                                                  int M, int N, int K) {
    __shared__ float As[BK][BM + 1];
    __shared__ float Bs[BK][BN + 1];
    const int tid  = threadIdx.x;
    const int tx   = tid & 15;
    const int ty   = tid >> 4;
    const int arow = tid >> 2;
    const int akb  = (tid & 3) * 4;
    const int brow = tid >> 4;
    const int bcol = (tid & 15) * 4;

    const int row0 = blockIdx.x * BM;
    const int col0 = blockIdx.y * BN;

    float acc[4][4] = {};
    const int nk = K / BK;
    for (int kt = 0; kt < nk; ++kt) {
        int garow = row0 + arow;
        if (garow < M) {
            const AT* ap = A + (size_t)garow * K + kt * BK + akb;
            #pragma unroll
            for (int i = 0; i < 4; ++i) As[akb + i][arow] = to_f32(ap[i]);
        } else {
            #pragma unroll
            for (int i = 0; i < 4; ++i) As[akb + i][arow] = 0.0f;
        }
        const float* bp = B + (size_t)(kt * BK + brow) * N + col0 + bcol;
        #pragma unroll
        for (int j = 0; j < 4; ++j) Bs[brow][bcol + j] = bp[j];
        __syncthreads();
        #pragma unroll
        for (int k = 0; k < BK; ++k) {
            float a[4], b[4];
            #pragma unroll
            for (int i = 0; i < 4; ++i) a[i] = As[k][ty * 4 + i];
            #pragma unroll
            for (int j = 0; j < 4; ++j) b[j] = Bs[k][tx * 4 + j];
            #pragma unroll
            for (int i = 0; i < 4; ++i)
                #pragma unroll
                for (int j = 0; j < 4; ++j)
                    acc[i][j] += a[i] * b[j];
        }
        __syncthreads();
    }
    #pragma unroll
    for (int i = 0; i < 4; ++i) {
        int row = row0 + ty * 4 + i;
        if (row >= M) continue;
        #pragma unroll
        for (int j = 0; j < 4; ++j) {
            int col = col0 + tx * 4 + j;
            C[(size_t)row * N + col] = __float2bfloat16(acc[i][j]);
        }
    }
}

// ---------------- layer-1 aggregation: wave per node, F=128 as bf16x2 ------
__global__ __launch_bounds__(256) void agg1_gather(const int* __restrict__ row_start,
                                                   const int* __restrict__ cnt,
                                                   const int* __restrict__ srcs,
                                                   const float* __restrict__ dinv,
                                                   const unsigned int* __restrict__ h,   // N x 64 (bf16x2)
                                                   const float* __restrict__ b1,
                                                   unsigned int* __restrict__ r,          // N x 64 (bf16x2)
                                                   int N) {
    int node = blockIdx.x * 4 + (threadIdx.x >> 6);
    if (node >= N) return;
    int lane = threadIdx.x & 63;
    float di = dinv[node];
    unsigned int hp = h[(size_t)node * 64 + lane];
    float sw = di * di;
    float accx = sw * bf16_lo(hp);
    float accy = sw * bf16_hi(hp);
    int beg = row_start[node];
    int num = cnt[node];
    for (int j = 0; j < num; ++j) {
        int sn = srcs[beg + j];
        float ns = di * dinv[sn];
        unsigned int p = h[(size_t)sn * 64 + lane];
        accx = fmaf(ns, bf16_lo(p), accx);
        accy = fmaf(ns, bf16_hi(p), accy);
    }
    float2 bb = *reinterpret_cast<const float2*>(&b1[lane * 2]);
    accx = fmaxf(accx + bb.x, 0.0f);
    accy = fmaxf(accy + bb.y, 0.0f);
    r[(size_t)node * 64 + lane] = pack_bf16(accx, accy);
}

// ---------------- layer-2 aggregation + bias + log_softmax, F=64 ----------
__global__ __launch_bounds__(256) void agg2_lsm(const int* __restrict__ row_start,
                                                const int* __restrict__ cnt,
                                                const int* __restrict__ srcs,
                                                const float* __restrict__ dinv,
                                                const __hip_bfloat16* __restrict__ h2,   // N x 64
                                                const float* __restrict__ b2,
                                                float* __restrict__ out, int N) {
    int node = blockIdx.x * 4 + (threadIdx.x >> 6);
    if (node >= N) return;
    int lane = threadIdx.x & 63;
    float di = dinv[node];
    float acc = di * di * __bfloat162float(h2[(size_t)node * 64 + lane]);
    int beg = row_start[node];
    int num = cnt[node];
    for (int j = 0; j < num; ++j) {
        int sn = srcs[beg + j];
        float ns = di * dinv[sn];
        acc = fmaf(ns, __bfloat162float(h2[(size_t)sn * 64 + lane]), acc);
    }
    float v = acc + b2[lane];
    float m = v;
    #pragma unroll
    for (int o = 32; o > 0; o >>= 1) m = fmaxf(m, __shfl_xor(m, o));
    float s = expf(v - m);
    #pragma unroll
    for (int o = 32; o > 0; o >>= 1) s += __shfl_xor(s, o);
    out[(size_t)node * 64 + lane] = v - m - logf(s);
}

// ---------------------------------------------------------------------------
extern "C" void kernel_launch(void* const* d_in, const int* in_sizes, int n_in,
                              void* d_out, int out_size, void* d_ws, size_t ws_size,
                              hipStream_t stream) {
    const float* x  = (const float*)d_in[0];
    const int*   ei = (const int*)d_in[1];
    const float* W1 = (const float*)d_in[2];
    const float* b1 = (const float*)d_in[3];
    const float* W2 = (const float*)d_in[4];
    const float* b2 = (const float*)d_in[5];
    float* out = (float*)d_out;

    const int N = in_sizes[0] / 512;   // 100000
    const int E = in_sizes[1] / 2;     // 1600000
    const int* src = ei;
    const int* dst = ei + E;

    // workspace layout
    char* ws = (char*)d_ws;
    size_t o = 0;
    auto take = [&](size_t bytes) { char* p = ws + o; o = (o + bytes + 255) & ~(size_t)255; return p; };
    int*            cnt       = (int*)take((size_t)N * 4);
    int*            bsum      = (int*)take(1024 * 4);
    int*            row_start = (int*)take((size_t)N * 4);
    int*            cursor    = (int*)take((size_t)N * 4);
    float*          dinv      = (float*)take((size_t)N * 4);
    int*            srcs      = (int*)take((size_t)E * 4);
    __hip_bfloat16* h         = (__hip_bfloat16*)take((size_t)N * 128 * 2);
    __hip_bfloat16* r         = (__hip_bfloat16*)take((size_t)N * 128 * 2);
    __hip_bfloat16* h2        = (__hip_bfloat16*)take((size_t)N * 64 * 2);

    const int nb = (N + 255) / 256;    // 391 <= 1024

    // CSR build
    hipMemsetAsync(cnt, 0, (size_t)N * 4, stream);
    count_deg<<<(E + 255) / 256, 256, 0, stream>>>(dst, cnt, E);
    scan_block_sums<<<nb, 256, 0, stream>>>(cnt, bsum, N);
    scan_bsums<<<1, 1024, 0, stream>>>(bsum, nb);
    scan_final<<<nb, 256, 0, stream>>>(cnt, bsum, row_start, cursor, dinv, N);
    scatter_edges<<<(E + 255) / 256, 256, 0, stream>>>(src, dst, cursor, srcs, E);

    // layer 1
    gemm_tiled<float><<<dim3((N + BM - 1) / BM, 128 / BN), 256, 0, stream>>>(x, W1, h, N, 128, 512);
    agg1_gather<<<(N + 3) / 4, 256, 0, stream>>>(row_start, cnt, srcs, dinv,
                                                 (const unsigned int*)h, b1,
                                                 (unsigned int*)r, N);

    // layer 2
    gemm_tiled<__hip_bfloat16><<<dim3((N + BM - 1) / BM, 1), 256, 0, stream>>>(r, W2, h2, N, 64, 128);
    agg2_lsm<<<(N + 3) / 4, 256, 0, stream>>>(row_start, cnt, srcs, dinv, h2, b2, out, N);
}

// Round 3
// 575.600 us; speedup vs baseline: 2.6144x; 1.4282x over previous
//
#include <hip/hip_runtime.h>
#include <hip/hip_bf16.h>

// ---------------------------------------------------------------------------
// GCN 2-layer forward, CSR-gather aggregation + MFMA bf16 GEMMs:
//   CSR build (count/scan/scatter), dinv = rsqrt(deg+1)
//   W1t = bf16(W1^T) [128][512], W2t = bf16(W2^T) [64][128]
//   h  = x @ W1      (MFMA bf16, f32 x converted in staging, bf16 store)
//   r  = relu(gather + dinv^2*h + b1)        (wave/node, bf16 store)
//   h2 = r @ W2      (MFMA bf16)
//   out = log_softmax(gather + dinv^2*h2 + b2)
// ---------------------------------------------------------------------------

typedef float f32x4 __attribute__((ext_vector_type(4)));
typedef short bf16x8 __attribute__((ext_vector_type(8)));

__device__ inline float bf16_lo(unsigned int p) {
    return __uint_as_float((p & 0xffffu) << 16);
}
__device__ inline float bf16_hi(unsigned int p) {
    return __uint_as_float(p & 0xffff0000u);
}
__device__ inline unsigned short bf16_bits(float f) {
    __hip_bfloat16 b = __float2bfloat16(f);
    return *reinterpret_cast<unsigned short*>(&b);
}
__device__ inline unsigned int pack_bf16(float a, float b) {
    return (unsigned int)bf16_bits(a) | ((unsigned int)bf16_bits(b) << 16);
}

// ---------------- CSR build ----------------
__global__ __launch_bounds__(256) void count_deg(const int* __restrict__ dst, int* __restrict__ cnt, int E) {
    int e = blockIdx.x * 256 + threadIdx.x;
    if (e < E) atomicAdd(&cnt[dst[e]], 1);
}

__global__ __launch_bounds__(256) void scan_block_sums(const int* __restrict__ cnt, int* __restrict__ bsum, int N) {
    __shared__ int s[256];
    int i = blockIdx.x * 256 + threadIdx.x;
    s[threadIdx.x] = (i < N) ? cnt[i] : 0;
    __syncthreads();
    for (int off = 128; off > 0; off >>= 1) {
        if (threadIdx.x < off) s[threadIdx.x] += s[threadIdx.x + off];
        __syncthreads();
    }
    if (threadIdx.x == 0) bsum[blockIdx.x] = s[0];
}

__global__ __launch_bounds__(1024) void scan_bsums(int* bsum, int nb) {
    __shared__ int s[1024];
    int v = (threadIdx.x < nb) ? bsum[threadIdx.x] : 0;
    s[threadIdx.x] = v;
    __syncthreads();
    for (int off = 1; off < 1024; off <<= 1) {
        int t = (threadIdx.x >= off) ? s[threadIdx.x - off] : 0;
        __syncthreads();
        s[threadIdx.x] += t;
        __syncthreads();
    }
    if (threadIdx.x < nb) bsum[threadIdx.x] = s[threadIdx.x] - v;  // exclusive
}

__global__ __launch_bounds__(256) void scan_final(const int* __restrict__ cnt, const int* __restrict__ bsum,
                                                  int* __restrict__ row_start, int* __restrict__ cursor,
                                                  float* __restrict__ dinv, int N) {
    __shared__ int s[256];
    int i = blockIdx.x * 256 + threadIdx.x;
    int v = (i < N) ? cnt[i] : 0;
    s[threadIdx.x] = v;
    __syncthreads();
    for (int off = 1; off < 256; off <<= 1) {
        int t = (threadIdx.x >= off) ? s[threadIdx.x - off] : 0;
        __syncthreads();
        s[threadIdx.x] += t;
        __syncthreads();
    }
    if (i < N) {
        int excl = s[threadIdx.x] - v + bsum[blockIdx.x];
        row_start[i] = excl;
        cursor[i]    = excl;
        dinv[i]      = rsqrtf((float)(v + 1));
    }
}

__global__ __launch_bounds__(256) void scatter_edges(const int* __restrict__ src, const int* __restrict__ dst,
                                                     int* __restrict__ cursor, int* __restrict__ srcs, int E) {
    int e = blockIdx.x * 256 + threadIdx.x;
    if (e < E) {
        int pos = atomicAdd(&cursor[dst[e]], 1);
        srcs[pos] = src[e];
    }
}

// ---------------- weight transpose + bf16 convert ----------------
__global__ __launch_bounds__(256) void conv_w1t(const float* __restrict__ W1, __hip_bfloat16* __restrict__ W1t) {
    int idx = blockIdx.x * 256 + threadIdx.x;      // 128*512
    int c = idx >> 9, k = idx & 511;
    W1t[idx] = __float2bfloat16(W1[k * 128 + c]);
}
__global__ __launch_bounds__(256) void conv_w2t(const float* __restrict__ W2, __hip_bfloat16* __restrict__ W2t) {
    int idx = blockIdx.x * 256 + threadIdx.x;      // 64*128
    int c = idx >> 7, k = idx & 127;
    W2t[idx] = __float2bfloat16(W2[k * 64 + c]);
}

// ---------------- GEMM1: [M,512]f32 x [512,128] -> [M,128]bf16 (MFMA) -----
// Block: 256 thr (4 waves, 2x2), tile 128x128, BK=64, K-steps=8.
// LDS swizzle: element (row,k) stored at col k ^ ((row&7)<<3)  (8-elem chunks)
__global__ __launch_bounds__(256) void gemm1_mfma(const float* __restrict__ A,          // [M][512]
                                                  const __hip_bfloat16* __restrict__ Bt, // [128][512] = W1^T
                                                  __hip_bfloat16* __restrict__ C,        // [M][128]
                                                  int M) {
    __shared__ __hip_bfloat16 As[128 * 64];
    __shared__ __hip_bfloat16 Bs[128 * 64];
    const int tid  = threadIdx.x;
    const int lane = tid & 63;
    const int wid  = tid >> 6;
    const int wr   = wid >> 1, wc = wid & 1;
    const int g    = lane >> 4, l15 = lane & 15;
    const int row0 = blockIdx.x * 128;

    f32x4 acc[4][4] = {};

    for (int kt = 0; kt < 8; ++kt) {
        // stage A: 128 rows x 64 k, f32 -> bf16
        #pragma unroll
        for (int it = 0; it < 8; ++it) {
            const int r = it * 16 + (tid >> 4);
            const int k = (tid & 15) * 4;
            int gr = row0 + r; if (gr >= M) gr = M - 1;
            const f32x4 v = *reinterpret_cast<const f32x4*>(A + (size_t)gr * 512 + kt * 64 + k);
            ushort4 p;
            p.x = bf16_bits(v.x); p.y = bf16_bits(v.y);
            p.z = bf16_bits(v.z); p.w = bf16_bits(v.w);
            const int kw = k ^ ((r & 7) << 3);
            *reinterpret_cast<ushort4*>(&As[r * 64 + kw]) = p;
        }
        // stage B: 128 cols x 64 k, bf16 copy
        #pragma unroll
        for (int it = 0; it < 4; ++it) {
            const int c = it * 32 + (tid >> 3);
            const int k = (tid & 7) * 8;
            const uint4 v = *reinterpret_cast<const uint4*>(Bt + (size_t)c * 512 + kt * 64 + k);
            const int kw = k ^ ((c & 7) << 3);
            *reinterpret_cast<uint4*>(&Bs[c * 64 + kw]) = v;
        }
        __syncthreads();
        #pragma unroll
        for (int kk = 0; kk < 2; ++kk) {
            bf16x8 af[4], bfr[4];
            const int k0 = kk * 32 + g * 8;
            #pragma unroll
            for (int i = 0; i < 4; ++i) {
                const int r = wr * 64 + i * 16 + l15;
                af[i] = *reinterpret_cast<const bf16x8*>(&As[r * 64 + (k0 ^ ((r & 7) << 3))]);
            }
            #pragma unroll
            for (int j = 0; j < 4; ++j) {
                const int c = wc * 64 + j * 16 + l15;
                bfr[j] = *reinterpret_cast<const bf16x8*>(&Bs[c * 64 + (k0 ^ ((c & 7) << 3))]);
            }
            #pragma unroll
            for (int i = 0; i < 4; ++i)
                #pragma unroll
                for (int j = 0; j < 4; ++j)
                    acc[i][j] = __builtin_amdgcn_mfma_f32_16x16x32_bf16(af[i], bfr[j], acc[i][j], 0, 0, 0);
        }
        __syncthreads();
    }
    // store C (D layout: col=lane&15, row=(lane>>4)*4+reg)
    #pragma unroll
    for (int i = 0; i < 4; ++i) {
        #pragma unroll
        for (int q = 0; q < 4; ++q) {
            const int row = row0 + wr * 64 + i * 16 + g * 4 + q;
            if (row < M) {
                #pragma unroll
                for (int j = 0; j < 4; ++j)
                    C[(size_t)row * 128 + wc * 64 + j * 16 + l15] = __float2bfloat16(acc[i][j][q]);
            }
        }
    }
}

// ---------------- GEMM2: [M,128]bf16 x [128,64] -> [M,64]bf16 (MFMA) ------
// Block: 256 thr (4 waves, rows split), tile 128x64, K=128 single shot.
__global__ __launch_bounds__(256) void gemm2_mfma(const __hip_bfloat16* __restrict__ A,  // [M][128]
                                                  const __hip_bfloat16* __restrict__ Bt, // [64][128] = W2^T
                                                  __hip_bfloat16* __restrict__ C,        // [M][64]
                                                  int M) {
    __shared__ __hip_bfloat16 As[128 * 128];
    __shared__ __hip_bfloat16 Bs[64 * 128];
    const int tid  = threadIdx.x;
    const int lane = tid & 63;
    const int w    = tid >> 6;
    const int g    = lane >> 4, l15 = lane & 15;
    const int row0 = blockIdx.x * 128;

    // stage A: 128 rows x 128 k
    #pragma unroll
    for (int it = 0; it < 8; ++it) {
        const int r = it * 16 + (tid >> 4);
        const int k = (tid & 15) * 8;
        int gr = row0 + r; if (gr >= M) gr = M - 1;
        const uint4 v = *reinterpret_cast<const uint4*>(A + (size_t)gr * 128 + k);
        *reinterpret_cast<uint4*>(&As[r * 128 + (k ^ ((r & 15) << 3))]) = v;
    }
    // stage B: 64 cols x 128 k
    #pragma unroll
    for (int it = 0; it < 4; ++it) {
        const int c = it * 16 + (tid >> 4);
        const int k = (tid & 15) * 8;
        const uint4 v = *reinterpret_cast<const uint4*>(Bt + (size_t)c * 128 + k);
        *reinterpret_cast<uint4*>(&Bs[c * 128 + (k ^ ((c & 15) << 3))]) = v;
    }
    __syncthreads();

    f32x4 acc[2][4] = {};
    #pragma unroll
    for (int kk = 0; kk < 4; ++kk) {
        bf16x8 af[2], bfr[4];
        const int k0 = kk * 32 + g * 8;
        #pragma unroll
        for (int i = 0; i < 2; ++i) {
            const int r = w * 32 + i * 16 + l15;
            af[i] = *reinterpret_cast<const bf16x8*>(&As[r * 128 + (k0 ^ ((r & 15) << 3))]);
        }
        #pragma unroll
        for (int j = 0; j < 4; ++j) {
            const int c = j * 16 + l15;
            bfr[j] = *reinterpret_cast<const bf16x8*>(&Bs[c * 128 + (k0 ^ ((c & 15) << 3))]);
        }
        #pragma unroll
        for (int i = 0; i < 2; ++i)
            #pragma unroll
            for (int j = 0; j < 4; ++j)
                acc[i][j] = __builtin_amdgcn_mfma_f32_16x16x32_bf16(af[i], bfr[j], acc[i][j], 0, 0, 0);
    }
    #pragma unroll
    for (int i = 0; i < 2; ++i) {
        #pragma unroll
        for (int q = 0; q < 4; ++q) {
            const int row = row0 + w * 32 + i * 16 + g * 4 + q;
            if (row < M) {
                #pragma unroll
                for (int j = 0; j < 4; ++j)
                    C[(size_t)row * 64 + j * 16 + l15] = __float2bfloat16(acc[i][j][q]);
            }
        }
    }
}

// ---------------- layer-1 aggregation: wave per node, F=128 as bf16x2 ------
__global__ __launch_bounds__(256) void agg1_gather(const int* __restrict__ row_start,
                                                   const int* __restrict__ cnt,
                                                   const int* __restrict__ srcs,
                                                   const float* __restrict__ dinv,
                                                   const unsigned int* __restrict__ h,   // N x 64 (bf16x2)
                                                   const float* __restrict__ b1,
                                                   unsigned int* __restrict__ r,          // N x 64 (bf16x2)
                                                   int N) {
    int node = blockIdx.x * 4 + (threadIdx.x >> 6);
    if (node >= N) return;
    int lane = threadIdx.x & 63;
    float di = dinv[node];
    unsigned int hp = h[(size_t)node * 64 + lane];
    float sw = di * di;
    float accx = sw * bf16_lo(hp);
    float accy = sw * bf16_hi(hp);
    int beg = row_start[node];
    int num = cnt[node];
    for (int j = 0; j < num; ++j) {
        int sn = srcs[beg + j];
        float ns = di * dinv[sn];
        unsigned int p = h[(size_t)sn * 64 + lane];
        accx = fmaf(ns, bf16_lo(p), accx);
        accy = fmaf(ns, bf16_hi(p), accy);
    }
    float2 bb = *reinterpret_cast<const float2*>(&b1[lane * 2]);
    accx = fmaxf(accx + bb.x, 0.0f);
    accy = fmaxf(accy + bb.y, 0.0f);
    r[(size_t)node * 64 + lane] = pack_bf16(accx, accy);
}

// ---------------- layer-2 aggregation + bias + log_softmax, F=64 ----------
__global__ __launch_bounds__(256) void agg2_lsm(const int* __restrict__ row_start,
                                                const int* __restrict__ cnt,
                                                const int* __restrict__ srcs,
                                                const float* __restrict__ dinv,
                                                const __hip_bfloat16* __restrict__ h2,   // N x 64
                                                const float* __restrict__ b2,
                                                float* __restrict__ out, int N) {
    int node = blockIdx.x * 4 + (threadIdx.x >> 6);
    if (node >= N) return;
    int lane = threadIdx.x & 63;
    float di = dinv[node];
    float acc = di * di * __bfloat162float(h2[(size_t)node * 64 + lane]);
    int beg = row_start[node];
    int num = cnt[node];
    for (int j = 0; j < num; ++j) {
        int sn = srcs[beg + j];
        float ns = di * dinv[sn];
        acc = fmaf(ns, __bfloat162float(h2[(size_t)sn * 64 + lane]), acc);
    }
    float v = acc + b2[lane];
    float m = v;
    #pragma unroll
    for (int o = 32; o > 0; o >>= 1) m = fmaxf(m, __shfl_xor(m, o));
    float s = expf(v - m);
    #pragma unroll
    for (int o = 32; o > 0; o >>= 1) s += __shfl_xor(s, o);
    out[(size_t)node * 64 + lane] = v - m - logf(s);
}

// ---------------------------------------------------------------------------
extern "C" void kernel_launch(void* const* d_in, const int* in_sizes, int n_in,
                              void* d_out, int out_size, void* d_ws, size_t ws_size,
                              hipStream_t stream) {
    const float* x  = (const float*)d_in[0];
    const int*   ei = (const int*)d_in[1];
    const float* W1 = (const float*)d_in[2];
    const float* b1 = (const float*)d_in[3];
    const float* W2 = (const float*)d_in[4];
    const float* b2 = (const float*)d_in[5];
    float* out = (float*)d_out;

    const int N = in_sizes[0] / 512;   // 100000
    const int E = in_sizes[1] / 2;     // 1600000
    const int* src = ei;
    const int* dst = ei + E;

    // workspace layout
    char* ws = (char*)d_ws;
    size_t o = 0;
    auto take = [&](size_t bytes) { char* p = ws + o; o = (o + bytes + 255) & ~(size_t)255; return p; };
    int*            cnt       = (int*)take((size_t)N * 4);
    int*            bsum      = (int*)take(1024 * 4);
    int*            row_start = (int*)take((size_t)N * 4);
    int*            cursor    = (int*)take((size_t)N * 4);
    float*          dinv      = (float*)take((size_t)N * 4);
    int*            srcs      = (int*)take((size_t)E * 4);
    __hip_bfloat16* W1t       = (__hip_bfloat16*)take((size_t)128 * 512 * 2);
    __hip_bfloat16* W2t       = (__hip_bfloat16*)take((size_t)64 * 128 * 2);
    __hip_bfloat16* h         = (__hip_bfloat16*)take((size_t)N * 128 * 2);
    __hip_bfloat16* r         = (__hip_bfloat16*)take((size_t)N * 128 * 2);
    __hip_bfloat16* h2        = (__hip_bfloat16*)take((size_t)N * 64 * 2);

    const int nb = (N + 255) / 256;    // 391 <= 1024
    const int mb = (N + 127) / 128;    // GEMM row blocks

    // CSR build
    hipMemsetAsync(cnt, 0, (size_t)N * 4, stream);
    count_deg<<<(E + 255) / 256, 256, 0, stream>>>(dst, cnt, E);
    scan_block_sums<<<nb, 256, 0, stream>>>(cnt, bsum, N);
    scan_bsums<<<1, 1024, 0, stream>>>(bsum, nb);
    scan_final<<<nb, 256, 0, stream>>>(cnt, bsum, row_start, cursor, dinv, N);
    scatter_edges<<<(E + 255) / 256, 256, 0, stream>>>(src, dst, cursor, srcs, E);

    // weights
    conv_w1t<<<(128 * 512) / 256, 256, 0, stream>>>(W1, W1t);
    conv_w2t<<<(64 * 128) / 256, 256, 0, stream>>>(W2, W2t);

    // layer 1
    gemm1_mfma<<<mb, 256, 0, stream>>>(x, W1t, h, N);
    agg1_gather<<<(N + 3) / 4, 256, 0, stream>>>(row_start, cnt, srcs, dinv,
                                                 (const unsigned int*)h, b1,
                                                 (unsigned int*)r, N);

    // layer 2
    gemm2_mfma<<<mb, 256, 0, stream>>>(r, W2t, h2, N);
    agg2_lsm<<<(N + 3) / 4, 256, 0, stream>>>(row_start, cnt, srcs, dinv, h2, b2, out, N);
}

// Round 4
// 415.479 us; speedup vs baseline: 3.6219x; 1.3854x over previous
//
#include <hip/hip_runtime.h>
#include <hip/hip_bf16.h>

// ---------------------------------------------------------------------------
// GCN 2-layer forward. CSR gather + MFMA bf16 GEMMs + factorized norm:
//   h'  = dinv * (x @ W1)        (dinv folded into GEMM1 epilogue, bf16)
//   r   = relu(di*(h'[n] + sum h'[src]) + b1)     (4 edges in flight / wave)
//   h2' = dinv * (r @ W2)        (GEMM2 epilogue, bf16)
//   out = log_softmax(di*(h2'[n] + sum h2'[src]) + b2)
// ---------------------------------------------------------------------------

typedef float f32x4 __attribute__((ext_vector_type(4)));
typedef short bf16x8 __attribute__((ext_vector_type(8)));

__device__ inline float bf16_lo(unsigned int p) {
    return __uint_as_float((p & 0xffffu) << 16);
}
__device__ inline float bf16_hi(unsigned int p) {
    return __uint_as_float(p & 0xffff0000u);
}
__device__ inline unsigned short bf16_bits(float f) {
    __hip_bfloat16 b = __float2bfloat16(f);
    return *reinterpret_cast<unsigned short*>(&b);
}
__device__ inline unsigned int pack_bf16(float a, float b) {
    return (unsigned int)bf16_bits(a) | ((unsigned int)bf16_bits(b) << 16);
}

// ---------------- CSR build ----------------
__global__ __launch_bounds__(256) void count_deg(const int* __restrict__ dst, int* __restrict__ cnt, int E) {
    int e = blockIdx.x * 256 + threadIdx.x;
    if (e < E) atomicAdd(&cnt[dst[e]], 1);
}

__global__ __launch_bounds__(256) void scan_block_sums(const int* __restrict__ cnt, int* __restrict__ bsum, int N) {
    __shared__ int s[256];
    int i = blockIdx.x * 256 + threadIdx.x;
    s[threadIdx.x] = (i < N) ? cnt[i] : 0;
    __syncthreads();
    for (int off = 128; off > 0; off >>= 1) {
        if (threadIdx.x < off) s[threadIdx.x] += s[threadIdx.x + off];
        __syncthreads();
    }
    if (threadIdx.x == 0) bsum[blockIdx.x] = s[0];
}

__global__ __launch_bounds__(1024) void scan_bsums(int* bsum, int nb) {
    __shared__ int s[1024];
    int v = (threadIdx.x < nb) ? bsum[threadIdx.x] : 0;
    s[threadIdx.x] = v;
    __syncthreads();
    for (int off = 1; off < 1024; off <<= 1) {
        int t = (threadIdx.x >= off) ? s[threadIdx.x - off] : 0;
        __syncthreads();
        s[threadIdx.x] += t;
        __syncthreads();
    }
    if (threadIdx.x < nb) bsum[threadIdx.x] = s[threadIdx.x] - v;  // exclusive
}

__global__ __launch_bounds__(256) void scan_final(const int* __restrict__ cnt, const int* __restrict__ bsum,
                                                  int* __restrict__ row_start, int* __restrict__ cursor,
                                                  float* __restrict__ dinv, int N) {
    __shared__ int s[256];
    int i = blockIdx.x * 256 + threadIdx.x;
    int v = (i < N) ? cnt[i] : 0;
    s[threadIdx.x] = v;
    __syncthreads();
    for (int off = 1; off < 256; off <<= 1) {
        int t = (threadIdx.x >= off) ? s[threadIdx.x - off] : 0;
        __syncthreads();
        s[threadIdx.x] += t;
        __syncthreads();
    }
    if (i < N) {
        int excl = s[threadIdx.x] - v + bsum[blockIdx.x];
        row_start[i] = excl;
        cursor[i]    = excl;
        dinv[i]      = rsqrtf((float)(v + 1));
    }
}

__global__ __launch_bounds__(256) void scatter_edges(const int* __restrict__ src, const int* __restrict__ dst,
                                                     int* __restrict__ cursor, int* __restrict__ srcs, int E) {
    int e = blockIdx.x * 256 + threadIdx.x;
    if (e < E) {
        int pos = atomicAdd(&cursor[dst[e]], 1);
        srcs[pos] = src[e];
    }
}

// ---------------- weight transpose + bf16 convert ----------------
__global__ __launch_bounds__(256) void conv_w1t(const float* __restrict__ W1, __hip_bfloat16* __restrict__ W1t) {
    int idx = blockIdx.x * 256 + threadIdx.x;      // 128*512
    int c = idx >> 9, k = idx & 511;
    W1t[idx] = __float2bfloat16(W1[k * 128 + c]);
}
__global__ __launch_bounds__(256) void conv_w2t(const float* __restrict__ W2, __hip_bfloat16* __restrict__ W2t) {
    int idx = blockIdx.x * 256 + threadIdx.x;      // 64*128
    int c = idx >> 7, k = idx & 127;
    W2t[idx] = __float2bfloat16(W2[k * 64 + c]);
}

// ---------------- GEMM1: h' = dinv * (x @ W1)  (MFMA bf16) ----------------
__global__ __launch_bounds__(256) void gemm1_mfma(const float* __restrict__ A,          // [M][512]
                                                  const __hip_bfloat16* __restrict__ Bt, // [128][512]
                                                  const float* __restrict__ dinv,
                                                  __hip_bfloat16* __restrict__ C,        // [M][128]
                                                  int M) {
    __shared__ __hip_bfloat16 As[128 * 64];
    __shared__ __hip_bfloat16 Bs[128 * 64];
    __shared__ float sdinv[128];
    const int tid  = threadIdx.x;
    const int lane = tid & 63;
    const int wid  = tid >> 6;
    const int wr   = wid >> 1, wc = wid & 1;
    const int g    = lane >> 4, l15 = lane & 15;
    const int row0 = blockIdx.x * 128;

    if (tid < 128) {
        int gr = row0 + tid;
        sdinv[tid] = dinv[gr < M ? gr : M - 1];
    }

    f32x4 acc[4][4] = {};

    for (int kt = 0; kt < 8; ++kt) {
        #pragma unroll
        for (int it = 0; it < 8; ++it) {
            const int r = it * 16 + (tid >> 4);
            const int k = (tid & 15) * 4;
            int gr = row0 + r; if (gr >= M) gr = M - 1;
            const f32x4 v = *reinterpret_cast<const f32x4*>(A + (size_t)gr * 512 + kt * 64 + k);
            ushort4 p;
            p.x = bf16_bits(v.x); p.y = bf16_bits(v.y);
            p.z = bf16_bits(v.z); p.w = bf16_bits(v.w);
            const int kw = k ^ ((r & 7) << 3);
            *reinterpret_cast<ushort4*>(&As[r * 64 + kw]) = p;
        }
        #pragma unroll
        for (int it = 0; it < 4; ++it) {
            const int c = it * 32 + (tid >> 3);
            const int k = (tid & 7) * 8;
            const uint4 v = *reinterpret_cast<const uint4*>(Bt + (size_t)c * 512 + kt * 64 + k);
            const int kw = k ^ ((c & 7) << 3);
            *reinterpret_cast<uint4*>(&Bs[c * 64 + kw]) = v;
        }
        __syncthreads();
        #pragma unroll
        for (int kk = 0; kk < 2; ++kk) {
            bf16x8 af[4], bfr[4];
            const int k0 = kk * 32 + g * 8;
            #pragma unroll
            for (int i = 0; i < 4; ++i) {
                const int r = wr * 64 + i * 16 + l15;
                af[i] = *reinterpret_cast<const bf16x8*>(&As[r * 64 + (k0 ^ ((r & 7) << 3))]);
            }
            #pragma unroll
            for (int j = 0; j < 4; ++j) {
                const int c = wc * 64 + j * 16 + l15;
                bfr[j] = *reinterpret_cast<const bf16x8*>(&Bs[c * 64 + (k0 ^ ((c & 7) << 3))]);
            }
            #pragma unroll
            for (int i = 0; i < 4; ++i)
                #pragma unroll
                for (int j = 0; j < 4; ++j)
                    acc[i][j] = __builtin_amdgcn_mfma_f32_16x16x32_bf16(af[i], bfr[j], acc[i][j], 0, 0, 0);
        }
        __syncthreads();
    }
    #pragma unroll
    for (int i = 0; i < 4; ++i) {
        #pragma unroll
        for (int q = 0; q < 4; ++q) {
            const int lr  = wr * 64 + i * 16 + g * 4 + q;
            const int row = row0 + lr;
            if (row < M) {
                const float dv = sdinv[lr];
                #pragma unroll
                for (int j = 0; j < 4; ++j)
                    C[(size_t)row * 128 + wc * 64 + j * 16 + l15] = __float2bfloat16(acc[i][j][q] * dv);
            }
        }
    }
}

// ---------------- GEMM2: h2' = dinv * (r @ W2)  (MFMA bf16) ---------------
__global__ __launch_bounds__(256) void gemm2_mfma(const __hip_bfloat16* __restrict__ A,  // [M][128]
                                                  const __hip_bfloat16* __restrict__ Bt, // [64][128]
                                                  const float* __restrict__ dinv,
                                                  __hip_bfloat16* __restrict__ C,        // [M][64]
                                                  int M) {
    __shared__ __hip_bfloat16 As[128 * 128];
    __shared__ __hip_bfloat16 Bs[64 * 128];
    __shared__ float sdinv[128];
    const int tid  = threadIdx.x;
    const int lane = tid & 63;
    const int w    = tid >> 6;
    const int g    = lane >> 4, l15 = lane & 15;
    const int row0 = blockIdx.x * 128;

    if (tid < 128) {
        int gr = row0 + tid;
        sdinv[tid] = dinv[gr < M ? gr : M - 1];
    }

    #pragma unroll
    for (int it = 0; it < 8; ++it) {
        const int r = it * 16 + (tid >> 4);
        const int k = (tid & 15) * 8;
        int gr = row0 + r; if (gr >= M) gr = M - 1;
        const uint4 v = *reinterpret_cast<const uint4*>(A + (size_t)gr * 128 + k);
        *reinterpret_cast<uint4*>(&As[r * 128 + (k ^ ((r & 15) << 3))]) = v;
    }
    #pragma unroll
    for (int it = 0; it < 4; ++it) {
        const int c = it * 16 + (tid >> 4);
        const int k = (tid & 15) * 8;
        const uint4 v = *reinterpret_cast<const uint4*>(Bt + (size_t)c * 128 + k);
        *reinterpret_cast<uint4*>(&Bs[c * 128 + (k ^ ((c & 15) << 3))]) = v;
    }
    __syncthreads();

    f32x4 acc[2][4] = {};
    #pragma unroll
    for (int kk = 0; kk < 4; ++kk) {
        bf16x8 af[2], bfr[4];
        const int k0 = kk * 32 + g * 8;
        #pragma unroll
        for (int i = 0; i < 2; ++i) {
            const int r = w * 32 + i * 16 + l15;
            af[i] = *reinterpret_cast<const bf16x8*>(&As[r * 128 + (k0 ^ ((r & 15) << 3))]);
        }
        #pragma unroll
        for (int j = 0; j < 4; ++j) {
            const int c = j * 16 + l15;
            bfr[j] = *reinterpret_cast<const bf16x8*>(&Bs[c * 128 + (k0 ^ ((c & 15) << 3))]);
        }
        #pragma unroll
        for (int i = 0; i < 2; ++i)
            #pragma unroll
            for (int j = 0; j < 4; ++j)
                acc[i][j] = __builtin_amdgcn_mfma_f32_16x16x32_bf16(af[i], bfr[j], acc[i][j], 0, 0, 0);
    }
    #pragma unroll
    for (int i = 0; i < 2; ++i) {
        #pragma unroll
        for (int q = 0; q < 4; ++q) {
            const int lr  = w * 32 + i * 16 + g * 4 + q;
            const int row = row0 + lr;
            if (row < M) {
                const float dv = sdinv[lr];
                #pragma unroll
                for (int j = 0; j < 4; ++j)
                    C[(size_t)row * 64 + j * 16 + l15] = __float2bfloat16(acc[i][j][q] * dv);
            }
        }
    }
}

// ------- layer-1 aggregation: wave/node, 4 edge slots x 16 lanes x uint4 ---
__global__ __launch_bounds__(256) void agg1_gather4(const int* __restrict__ row_start,
                                                    const int* __restrict__ cnt,
                                                    const int* __restrict__ srcs,
                                                    const float* __restrict__ dinv,
                                                    const uint4* __restrict__ h4,   // [N][16] (128 bf16)
                                                    const float* __restrict__ b1,
                                                    uint4* __restrict__ r4,          // [N][16]
                                                    int N) {
    int node = blockIdx.x * 4 + (threadIdx.x >> 6);
    if (node >= N) return;
    const int lane = threadIdx.x & 63;
    const int s = lane >> 4, li = lane & 15;

    float acc[8] = {};
    if (s == 0) {   // self-loop term counted once
        uint4 v = h4[(size_t)node * 16 + li];
        acc[0] += bf16_lo(v.x); acc[1] += bf16_hi(v.x);
        acc[2] += bf16_lo(v.y); acc[3] += bf16_hi(v.y);
        acc[4] += bf16_lo(v.z); acc[5] += bf16_hi(v.z);
        acc[6] += bf16_lo(v.w); acc[7] += bf16_hi(v.w);
    }
    const int beg = row_start[node];
    const int num = cnt[node];
    for (int j = 0; j < num; j += 4) {
        const int jj = j + s;
        if (jj < num) {
            const int sn = srcs[beg + jj];
            uint4 v = h4[(size_t)sn * 16 + li];
            acc[0] += bf16_lo(v.x); acc[1] += bf16_hi(v.x);
            acc[2] += bf16_lo(v.y); acc[3] += bf16_hi(v.y);
            acc[4] += bf16_lo(v.z); acc[5] += bf16_hi(v.z);
            acc[6] += bf16_lo(v.w); acc[7] += bf16_hi(v.w);
        }
    }
    #pragma unroll
    for (int t = 0; t < 8; ++t) {
        acc[t] += __shfl_xor(acc[t], 16);
        acc[t] += __shfl_xor(acc[t], 32);
    }
    if (s == 0) {
        const float di = dinv[node];
        const float4 bb0 = reinterpret_cast<const float4*>(b1)[li * 2];
        const float4 bb1 = reinterpret_cast<const float4*>(b1)[li * 2 + 1];
        uint4 o;
        o.x = pack_bf16(fmaxf(fmaf(di, acc[0], bb0.x), 0.0f), fmaxf(fmaf(di, acc[1], bb0.y), 0.0f));
        o.y = pack_bf16(fmaxf(fmaf(di, acc[2], bb0.z), 0.0f), fmaxf(fmaf(di, acc[3], bb0.w), 0.0f));
        o.z = pack_bf16(fmaxf(fmaf(di, acc[4], bb1.x), 0.0f), fmaxf(fmaf(di, acc[5], bb1.y), 0.0f));
        o.w = pack_bf16(fmaxf(fmaf(di, acc[6], bb1.z), 0.0f), fmaxf(fmaf(di, acc[7], bb1.w), 0.0f));
        r4[(size_t)node * 16 + li] = o;
    }
}

// ------- layer-2 aggregation + bias + log_softmax, 4 slots x 16 x uint2 ----
__global__ __launch_bounds__(256) void agg2_lsm4(const int* __restrict__ row_start,
                                                 const int* __restrict__ cnt,
                                                 const int* __restrict__ srcs,
                                                 const float* __restrict__ dinv,
                                                 const uint2* __restrict__ h2v,  // [N][16] (64 bf16)
                                                 const float* __restrict__ b2,
                                                 float* __restrict__ out, int N) {
    int node = blockIdx.x * 4 + (threadIdx.x >> 6);
    if (node >= N) return;
    const int lane = threadIdx.x & 63;
    const int s = lane >> 4, li = lane & 15;

    float acc[4] = {};
    if (s == 0) {
        uint2 v = h2v[(size_t)node * 16 + li];
        acc[0] += bf16_lo(v.x); acc[1] += bf16_hi(v.x);
        acc[2] += bf16_lo(v.y); acc[3] += bf16_hi(v.y);
    }
    const int beg = row_start[node];
    const int num = cnt[node];
    for (int j = 0; j < num; j += 4) {
        const int jj = j + s;
        if (jj < num) {
            const int sn = srcs[beg + jj];
            uint2 v = h2v[(size_t)sn * 16 + li];
            acc[0] += bf16_lo(v.x); acc[1] += bf16_hi(v.x);
            acc[2] += bf16_lo(v.y); acc[3] += bf16_hi(v.y);
        }
    }
    #pragma unroll
    for (int t = 0; t < 4; ++t) {
        acc[t] += __shfl_xor(acc[t], 16);
        acc[t] += __shfl_xor(acc[t], 32);
    }
    const float di = dinv[node];
    const float4 bb = reinterpret_cast<const float4*>(b2)[li];
    float v0 = fmaf(di, acc[0], bb.x);
    float v1 = fmaf(di, acc[1], bb.y);
    float v2 = fmaf(di, acc[2], bb.z);
    float v3 = fmaf(di, acc[3], bb.w);
    float m = fmaxf(fmaxf(v0, v1), fmaxf(v2, v3));
    #pragma unroll
    for (int o = 8; o > 0; o >>= 1) m = fmaxf(m, __shfl_xor(m, o));
    float es = expf(v0 - m) + expf(v1 - m) + expf(v2 - m) + expf(v3 - m);
    #pragma unroll
    for (int o = 8; o > 0; o >>= 1) es += __shfl_xor(es, o);
    if (s == 0) {
        const float lse = m + logf(es);
        float4 r;
        r.x = v0 - lse; r.y = v1 - lse; r.z = v2 - lse; r.w = v3 - lse;
        reinterpret_cast<float4*>(out)[(size_t)node * 16 + li] = r;
    }
}

// ---------------------------------------------------------------------------
extern "C" void kernel_launch(void* const* d_in, const int* in_sizes, int n_in,
                              void* d_out, int out_size, void* d_ws, size_t ws_size,
                              hipStream_t stream) {
    const float* x  = (const float*)d_in[0];
    const int*   ei = (const int*)d_in[1];
    const float* W1 = (const float*)d_in[2];
    const float* b1 = (const float*)d_in[3];
    const float* W2 = (const float*)d_in[4];
    const float* b2 = (const float*)d_in[5];
    float* out = (float*)d_out;

    const int N = in_sizes[0] / 512;   // 100000
    const int E = in_sizes[1] / 2;     // 1600000
    const int* src = ei;
    const int* dst = ei + E;

    // workspace layout
    char* ws = (char*)d_ws;
    size_t o = 0;
    auto take = [&](size_t bytes) { char* p = ws + o; o = (o + bytes + 255) & ~(size_t)255; return p; };
    int*            cnt       = (int*)take((size_t)N * 4);
    int*            bsum      = (int*)take(1024 * 4);
    int*            row_start = (int*)take((size_t)N * 4);
    int*            cursor    = (int*)take((size_t)N * 4);
    float*          dinv      = (float*)take((size_t)N * 4);
    int*            srcs      = (int*)take((size_t)E * 4);
    __hip_bfloat16* W1t       = (__hip_bfloat16*)take((size_t)128 * 512 * 2);
    __hip_bfloat16* W2t       = (__hip_bfloat16*)take((size_t)64 * 128 * 2);
    __hip_bfloat16* h         = (__hip_bfloat16*)take((size_t)N * 128 * 2);   // h' = dinv*h
    __hip_bfloat16* r         = (__hip_bfloat16*)take((size_t)N * 128 * 2);
    __hip_bfloat16* h2        = (__hip_bfloat16*)take((size_t)N * 64 * 2);    // h2' = dinv*h2

    const int nb = (N + 255) / 256;
    const int mb = (N + 127) / 128;

    // CSR build
    hipMemsetAsync(cnt, 0, (size_t)N * 4, stream);
    count_deg<<<(E + 255) / 256, 256, 0, stream>>>(dst, cnt, E);
    scan_block_sums<<<nb, 256, 0, stream>>>(cnt, bsum, N);
    scan_bsums<<<1, 1024, 0, stream>>>(bsum, nb);
    scan_final<<<nb, 256, 0, stream>>>(cnt, bsum, row_start, cursor, dinv, N);
    scatter_edges<<<(E + 255) / 256, 256, 0, stream>>>(src, dst, cursor, srcs, E);

    // weights
    conv_w1t<<<(128 * 512) / 256, 256, 0, stream>>>(W1, W1t);
    conv_w2t<<<(64 * 128) / 256, 256, 0, stream>>>(W2, W2t);

    // layer 1
    gemm1_mfma<<<mb, 256, 0, stream>>>(x, W1t, dinv, h, N);
    agg1_gather4<<<(N + 3) / 4, 256, 0, stream>>>(row_start, cnt, srcs, dinv,
                                                  (const uint4*)h, b1, (uint4*)r, N);

    // layer 2
    gemm2_mfma<<<mb, 256, 0, stream>>>(r, W2t, dinv, h2, N);
    agg2_lsm4<<<(N + 3) / 4, 256, 0, stream>>>(row_start, cnt, srcs, dinv,
                                               (const uint2*)h2, b2, out, N);
}

// Round 5
// 276.951 us; speedup vs baseline: 5.4336x; 1.5002x over previous
//
#include <hip/hip_runtime.h>
#include <hip/hip_bf16.h>

// ---------------------------------------------------------------------------
// GCN 2-layer forward. Bucketed-counting-sort CSR + MFMA bf16 GEMMs:
//   bucket = dst>>8 (391 buckets x 256 nodes)
//   hist -> scan -> bucket-major edge scatter -> per-bucket CSR (LDS only)
//   h'  = dinv * (x @ W1)   (bf16)     r = relu(di*(h'[n]+sum h'[src])+b1)
//   h2' = dinv * (r @ W2)   (bf16)     out = log_softmax(di*(...)+b2)
// ---------------------------------------------------------------------------

typedef float f32x4 __attribute__((ext_vector_type(4)));
typedef short bf16x8 __attribute__((ext_vector_type(8)));

__device__ inline float bf16_lo(unsigned int p) {
    return __uint_as_float((p & 0xffffu) << 16);
}
__device__ inline float bf16_hi(unsigned int p) {
    return __uint_as_float(p & 0xffff0000u);
}
__device__ inline unsigned short bf16_bits(float f) {
    __hip_bfloat16 b = __float2bfloat16(f);
    return *reinterpret_cast<unsigned short*>(&b);
}
__device__ inline unsigned int pack_bf16(float a, float b) {
    return (unsigned int)bf16_bits(a) | ((unsigned int)bf16_bits(b) << 16);
}

#define EB 4096            // edges per block in bucketing passes
#define BSHIFT 8           // bucket = dst >> 8

// ---------------- pass 1: per-(block,bucket) histogram ----------------
__global__ __launch_bounds__(256) void hist_bucket(const int* __restrict__ dst,
                                                   int* __restrict__ counts,   // [NBUCKET][NB_E]
                                                   int NB_E, int NBUCKET, int E) {
    __shared__ int hist[512];
    const int tid = threadIdx.x;
    for (int i = tid; i < NBUCKET; i += 256) hist[i] = 0;
    __syncthreads();
    const int e0 = blockIdx.x * EB;
    const int e1 = min(e0 + EB, E);
    for (int e = e0 + tid; e < e1; e += 256)
        atomicAdd(&hist[dst[e] >> BSHIFT], 1);
    __syncthreads();
    for (int i = tid; i < NBUCKET; i += 256)
        counts[(size_t)i * NB_E + blockIdx.x] = hist[i];
}

// ---------------- scan machinery (2-level, exclusive) ----------------
__global__ __launch_bounds__(256) void scan_block_sums(const int* __restrict__ v, int* __restrict__ bsum, int T) {
    __shared__ int s[256];
    int i = blockIdx.x * 256 + threadIdx.x;
    s[threadIdx.x] = (i < T) ? v[i] : 0;
    __syncthreads();
    for (int off = 128; off > 0; off >>= 1) {
        if (threadIdx.x < off) s[threadIdx.x] += s[threadIdx.x + off];
        __syncthreads();
    }
    if (threadIdx.x == 0) bsum[blockIdx.x] = s[0];
}

__global__ __launch_bounds__(1024) void scan_bsums(int* bsum, int nb) {
    __shared__ int s[1024];
    int v = (threadIdx.x < nb) ? bsum[threadIdx.x] : 0;
    s[threadIdx.x] = v;
    __syncthreads();
    for (int off = 1; off < 1024; off <<= 1) {
        int t = (threadIdx.x >= off) ? s[threadIdx.x - off] : 0;
        __syncthreads();
        s[threadIdx.x] += t;
        __syncthreads();
    }
    if (threadIdx.x < nb) bsum[threadIdx.x] = s[threadIdx.x] - v;  // exclusive
}

__global__ __launch_bounds__(256) void scan_offs(const int* __restrict__ v, const int* __restrict__ bsum,
                                                 int* __restrict__ offs, int T) {
    __shared__ int s[256];
    int i = blockIdx.x * 256 + threadIdx.x;
    int x = (i < T) ? v[i] : 0;
    s[threadIdx.x] = x;
    __syncthreads();
    for (int off = 1; off < 256; off <<= 1) {
        int t = (threadIdx.x >= off) ? s[threadIdx.x - off] : 0;
        __syncthreads();
        s[threadIdx.x] += t;
        __syncthreads();
    }
    if (i < T) offs[i] = s[threadIdx.x] - x + bsum[blockIdx.x];
}

// ---------------- pass 3: bucket-major edge materialization ----------------
__global__ __launch_bounds__(256) void scatter_bucketed(const int* __restrict__ src,
                                                        const int* __restrict__ dst,
                                                        const int* __restrict__ offs,  // [NBUCKET][NB_E]
                                                        uint2* __restrict__ ebuf,      // (src,dst) bucket-major
                                                        int NB_E, int NBUCKET, int E) {
    __shared__ int lcur[512];
    const int tid = threadIdx.x;
    for (int i = tid; i < NBUCKET; i += 256)
        lcur[i] = offs[(size_t)i * NB_E + blockIdx.x];
    __syncthreads();
    const int e0 = blockIdx.x * EB;
    const int e1 = min(e0 + EB, E);
    for (int e = e0 + tid; e < e1; e += 256) {
        const int d = dst[e];
        const int s = src[e];
        const int pos = atomicAdd(&lcur[d >> BSHIFT], 1);
        ebuf[pos] = make_uint2((unsigned)s, (unsigned)d);
    }
}

// ---------------- pass 4: per-bucket CSR finalize (all LDS) ----------------
__global__ __launch_bounds__(256) void bucket_csr(const uint2* __restrict__ ebuf,
                                                  const int* __restrict__ offs,
                                                  int* __restrict__ row_start,
                                                  int* __restrict__ cnt,
                                                  float* __restrict__ dinv,
                                                  int* __restrict__ srcs,
                                                  int NB_E, int NBUCKET, int N, int E) {
    __shared__ int lcnt[256];
    __shared__ int lscan[256];
    __shared__ int lcur[256];
    const int tid = threadIdx.x;
    const int b = blockIdx.x;
    const int node_base = b << BSHIFT;
    const int ebeg = offs[(size_t)b * NB_E];
    const int eend = (b + 1 < NBUCKET) ? offs[(size_t)(b + 1) * NB_E] : E;

    lcnt[tid] = 0;
    __syncthreads();
    for (int e = ebeg + tid; e < eend; e += 256)
        atomicAdd(&lcnt[ebuf[e].y - node_base], 1);
    __syncthreads();

    // exclusive scan of lcnt
    int v = lcnt[tid];
    lscan[tid] = v;
    __syncthreads();
    for (int off = 1; off < 256; off <<= 1) {
        int t = (tid >= off) ? lscan[tid - off] : 0;
        __syncthreads();
        lscan[tid] += t;
        __syncthreads();
    }
    const int excl = lscan[tid] - v;

    const int node = node_base + tid;
    if (node < N) {
        row_start[node] = ebeg + excl;
        cnt[node]       = v;
        dinv[node]      = rsqrtf((float)(v + 1));
    }
    lcur[tid] = excl;
    __syncthreads();

    for (int e = ebeg + tid; e < eend; e += 256) {
        const uint2 p = ebuf[e];
        const int pos = ebeg + atomicAdd(&lcur[p.y - node_base], 1);
        srcs[pos] = (int)p.x;
    }
}

// ---------------- weight transpose + bf16 convert ----------------
__global__ __launch_bounds__(256) void conv_w1t(const float* __restrict__ W1, __hip_bfloat16* __restrict__ W1t) {
    int idx = blockIdx.x * 256 + threadIdx.x;      // 128*512
    int c = idx >> 9, k = idx & 511;
    W1t[idx] = __float2bfloat16(W1[k * 128 + c]);
}
__global__ __launch_bounds__(256) void conv_w2t(const float* __restrict__ W2, __hip_bfloat16* __restrict__ W2t) {
    int idx = blockIdx.x * 256 + threadIdx.x;      // 64*128
    int c = idx >> 7, k = idx & 127;
    W2t[idx] = __float2bfloat16(W2[k * 64 + c]);
}

// ---------------- GEMM1: h' = dinv * (x @ W1)  (MFMA bf16) ----------------
__global__ __launch_bounds__(256) void gemm1_mfma(const float* __restrict__ A,          // [M][512]
                                                  const __hip_bfloat16* __restrict__ Bt, // [128][512]
                                                  const float* __restrict__ dinv,
                                                  __hip_bfloat16* __restrict__ C,        // [M][128]
                                                  int M) {
    __shared__ __hip_bfloat16 As[128 * 64];
    __shared__ __hip_bfloat16 Bs[128 * 64];
    __shared__ float sdinv[128];
    const int tid  = threadIdx.x;
    const int lane = tid & 63;
    const int wid  = tid >> 6;
    const int wr   = wid >> 1, wc = wid & 1;
    const int g    = lane >> 4, l15 = lane & 15;
    const int row0 = blockIdx.x * 128;

    if (tid < 128) {
        int gr = row0 + tid;
        sdinv[tid] = dinv[gr < M ? gr : M - 1];
    }

    f32x4 acc[4][4] = {};

    for (int kt = 0; kt < 8; ++kt) {
        #pragma unroll
        for (int it = 0; it < 8; ++it) {
            const int r = it * 16 + (tid >> 4);
            const int k = (tid & 15) * 4;
            int gr = row0 + r; if (gr >= M) gr = M - 1;
            const f32x4 v = *reinterpret_cast<const f32x4*>(A + (size_t)gr * 512 + kt * 64 + k);
            ushort4 p;
            p.x = bf16_bits(v.x); p.y = bf16_bits(v.y);
            p.z = bf16_bits(v.z); p.w = bf16_bits(v.w);
            const int kw = k ^ ((r & 7) << 3);
            *reinterpret_cast<ushort4*>(&As[r * 64 + kw]) = p;
        }
        #pragma unroll
        for (int it = 0; it < 4; ++it) {
            const int c = it * 32 + (tid >> 3);
            const int k = (tid & 7) * 8;
            const uint4 v = *reinterpret_cast<const uint4*>(Bt + (size_t)c * 512 + kt * 64 + k);
            const int kw = k ^ ((c & 7) << 3);
            *reinterpret_cast<uint4*>(&Bs[c * 64 + kw]) = v;
        }
        __syncthreads();
        #pragma unroll
        for (int kk = 0; kk < 2; ++kk) {
            bf16x8 af[4], bfr[4];
            const int k0 = kk * 32 + g * 8;
            #pragma unroll
            for (int i = 0; i < 4; ++i) {
                const int r = wr * 64 + i * 16 + l15;
                af[i] = *reinterpret_cast<const bf16x8*>(&As[r * 64 + (k0 ^ ((r & 7) << 3))]);
            }
            #pragma unroll
            for (int j = 0; j < 4; ++j) {
                const int c = wc * 64 + j * 16 + l15;
                bfr[j] = *reinterpret_cast<const bf16x8*>(&Bs[c * 64 + (k0 ^ ((c & 7) << 3))]);
            }
            #pragma unroll
            for (int i = 0; i < 4; ++i)
                #pragma unroll
                for (int j = 0; j < 4; ++j)
                    acc[i][j] = __builtin_amdgcn_mfma_f32_16x16x32_bf16(af[i], bfr[j], acc[i][j], 0, 0, 0);
        }
        __syncthreads();
    }
    #pragma unroll
    for (int i = 0; i < 4; ++i) {
        #pragma unroll
        for (int q = 0; q < 4; ++q) {
            const int lr  = wr * 64 + i * 16 + g * 4 + q;
            const int row = row0 + lr;
            if (row < M) {
                const float dv = sdinv[lr];
                #pragma unroll
                for (int j = 0; j < 4; ++j)
                    C[(size_t)row * 128 + wc * 64 + j * 16 + l15] = __float2bfloat16(acc[i][j][q] * dv);
            }
        }
    }
}

// ---------------- GEMM2: h2' = dinv * (r @ W2)  (MFMA bf16) ---------------
__global__ __launch_bounds__(256) void gemm2_mfma(const __hip_bfloat16* __restrict__ A,  // [M][128]
                                                  const __hip_bfloat16* __restrict__ Bt, // [64][128]
                                                  const float* __restrict__ dinv,
                                                  __hip_bfloat16* __restrict__ C,        // [M][64]
                                                  int M) {
    __shared__ __hip_bfloat16 As[128 * 128];
    __shared__ __hip_bfloat16 Bs[64 * 128];
    __shared__ float sdinv[128];
    const int tid  = threadIdx.x;
    const int lane = tid & 63;
    const int w    = tid >> 6;
    const int g    = lane >> 4, l15 = lane & 15;
    const int row0 = blockIdx.x * 128;

    if (tid < 128) {
        int gr = row0 + tid;
        sdinv[tid] = dinv[gr < M ? gr : M - 1];
    }

    #pragma unroll
    for (int it = 0; it < 8; ++it) {
        const int r = it * 16 + (tid >> 4);
        const int k = (tid & 15) * 8;
        int gr = row0 + r; if (gr >= M) gr = M - 1;
        const uint4 v = *reinterpret_cast<const uint4*>(A + (size_t)gr * 128 + k);
        *reinterpret_cast<uint4*>(&As[r * 128 + (k ^ ((r & 15) << 3))]) = v;
    }
    #pragma unroll
    for (int it = 0; it < 4; ++it) {
        const int c = it * 16 + (tid >> 4);
        const int k = (tid & 15) * 8;
        const uint4 v = *reinterpret_cast<const uint4*>(Bt + (size_t)c * 128 + k);
        *reinterpret_cast<uint4*>(&Bs[c * 128 + (k ^ ((c & 15) << 3))]) = v;
    }
    __syncthreads();

    f32x4 acc[2][4] = {};
    #pragma unroll
    for (int kk = 0; kk < 4; ++kk) {
        bf16x8 af[2], bfr[4];
        const int k0 = kk * 32 + g * 8;
        #pragma unroll
        for (int i = 0; i < 2; ++i) {
            const int r = w * 32 + i * 16 + l15;
            af[i] = *reinterpret_cast<const bf16x8*>(&As[r * 128 + (k0 ^ ((r & 15) << 3))]);
        }
        #pragma unroll
        for (int j = 0; j < 4; ++j) {
            const int c = j * 16 + l15;
            bfr[j] = *reinterpret_cast<const bf16x8*>(&Bs[c * 128 + (k0 ^ ((c & 15) << 3))]);
        }
        #pragma unroll
        for (int i = 0; i < 2; ++i)
            #pragma unroll
            for (int j = 0; j < 4; ++j)
                acc[i][j] = __builtin_amdgcn_mfma_f32_16x16x32_bf16(af[i], bfr[j], acc[i][j], 0, 0, 0);
    }
    #pragma unroll
    for (int i = 0; i < 2; ++i) {
        #pragma unroll
        for (int q = 0; q < 4; ++q) {
            const int lr  = w * 32 + i * 16 + g * 4 + q;
            const int row = row0 + lr;
            if (row < M) {
                const float dv = sdinv[lr];
                #pragma unroll
                for (int j = 0; j < 4; ++j)
                    C[(size_t)row * 64 + j * 16 + l15] = __float2bfloat16(acc[i][j][q] * dv);
            }
        }
    }
}

// ------- layer-1 aggregation: wave/node, 4 edge slots x 16 lanes x uint4 ---
__global__ __launch_bounds__(256) void agg1_gather4(const int* __restrict__ row_start,
                                                    const int* __restrict__ cnt,
                                                    const int* __restrict__ srcs,
                                                    const float* __restrict__ dinv,
                                                    const uint4* __restrict__ h4,   // [N][16] (128 bf16)
                                                    const float* __restrict__ b1,
                                                    uint4* __restrict__ r4,          // [N][16]
                                                    int N) {
    int node = blockIdx.x * 4 + (threadIdx.x >> 6);
    if (node >= N) return;
    const int lane = threadIdx.x & 63;
    const int s = lane >> 4, li = lane & 15;

    float acc[8] = {};
    if (s == 0) {   // self-loop term counted once
        uint4 v = h4[(size_t)node * 16 + li];
        acc[0] += bf16_lo(v.x); acc[1] += bf16_hi(v.x);
        acc[2] += bf16_lo(v.y); acc[3] += bf16_hi(v.y);
        acc[4] += bf16_lo(v.z); acc[5] += bf16_hi(v.z);
        acc[6] += bf16_lo(v.w); acc[7] += bf16_hi(v.w);
    }
    const int beg = row_start[node];
    const int num = cnt[node];
    for (int j = 0; j < num; j += 4) {
        const int jj = j + s;
        if (jj < num) {
            const int sn = srcs[beg + jj];
            uint4 v = h4[(size_t)sn * 16 + li];
            acc[0] += bf16_lo(v.x); acc[1] += bf16_hi(v.x);
            acc[2] += bf16_lo(v.y); acc[3] += bf16_hi(v.y);
            acc[4] += bf16_lo(v.z); acc[5] += bf16_hi(v.z);
            acc[6] += bf16_lo(v.w); acc[7] += bf16_hi(v.w);
        }
    }
    #pragma unroll
    for (int t = 0; t < 8; ++t) {
        acc[t] += __shfl_xor(acc[t], 16);
        acc[t] += __shfl_xor(acc[t], 32);
    }
    if (s == 0) {
        const float di = dinv[node];
        const float4 bb0 = reinterpret_cast<const float4*>(b1)[li * 2];
        const float4 bb1 = reinterpret_cast<const float4*>(b1)[li * 2 + 1];
        uint4 o;
        o.x = pack_bf16(fmaxf(fmaf(di, acc[0], bb0.x), 0.0f), fmaxf(fmaf(di, acc[1], bb0.y), 0.0f));
        o.y = pack_bf16(fmaxf(fmaf(di, acc[2], bb0.z), 0.0f), fmaxf(fmaf(di, acc[3], bb0.w), 0.0f));
        o.z = pack_bf16(fmaxf(fmaf(di, acc[4], bb1.x), 0.0f), fmaxf(fmaf(di, acc[5], bb1.y), 0.0f));
        o.w = pack_bf16(fmaxf(fmaf(di, acc[6], bb1.z), 0.0f), fmaxf(fmaf(di, acc[7], bb1.w), 0.0f));
        r4[(size_t)node * 16 + li] = o;
    }
}

// ------- layer-2 aggregation + bias + log_softmax, 4 slots x 16 x uint2 ----
__global__ __launch_bounds__(256) void agg2_lsm4(const int* __restrict__ row_start,
                                                 const int* __restrict__ cnt,
                                                 const int* __restrict__ srcs,
                                                 const float* __restrict__ dinv,
                                                 const uint2* __restrict__ h2v,  // [N][16] (64 bf16)
                                                 const float* __restrict__ b2,
                                                 float* __restrict__ out, int N) {
    int node = blockIdx.x * 4 + (threadIdx.x >> 6);
    if (node >= N) return;
    const int lane = threadIdx.x & 63;
    const int s = lane >> 4, li = lane & 15;

    float acc[4] = {};
    if (s == 0) {
        uint2 v = h2v[(size_t)node * 16 + li];
        acc[0] += bf16_lo(v.x); acc[1] += bf16_hi(v.x);
        acc[2] += bf16_lo(v.y); acc[3] += bf16_hi(v.y);
    }
    const int beg = row_start[node];
    const int num = cnt[node];
    for (int j = 0; j < num; j += 4) {
        const int jj = j + s;
        if (jj < num) {
            const int sn = srcs[beg + jj];
            uint2 v = h2v[(size_t)sn * 16 + li];
            acc[0] += bf16_lo(v.x); acc[1] += bf16_hi(v.x);
            acc[2] += bf16_lo(v.y); acc[3] += bf16_hi(v.y);
        }
    }
    #pragma unroll
    for (int t = 0; t < 4; ++t) {
        acc[t] += __shfl_xor(acc[t], 16);
        acc[t] += __shfl_xor(acc[t], 32);
    }
    const float di = dinv[node];
    const float4 bb = reinterpret_cast<const float4*>(b2)[li];
    float v0 = fmaf(di, acc[0], bb.x);
    float v1 = fmaf(di, acc[1], bb.y);
    float v2 = fmaf(di, acc[2], bb.z);
    float v3 = fmaf(di, acc[3], bb.w);
    float m = fmaxf(fmaxf(v0, v1), fmaxf(v2, v3));
    #pragma unroll
    for (int o = 8; o > 0; o >>= 1) m = fmaxf(m, __shfl_xor(m, o));
    float es = expf(v0 - m) + expf(v1 - m) + expf(v2 - m) + expf(v3 - m);
    #pragma unroll
    for (int o = 8; o > 0; o >>= 1) es += __shfl_xor(es, o);
    if (s == 0) {
        const float lse = m + logf(es);
        float4 r;
        r.x = v0 - lse; r.y = v1 - lse; r.z = v2 - lse; r.w = v3 - lse;
        reinterpret_cast<float4*>(out)[(size_t)node * 16 + li] = r;
    }
}

// ---------------------------------------------------------------------------
extern "C" void kernel_launch(void* const* d_in, const int* in_sizes, int n_in,
                              void* d_out, int out_size, void* d_ws, size_t ws_size,
                              hipStream_t stream) {
    const float* x  = (const float*)d_in[0];
    const int*   ei = (const int*)d_in[1];
    const float* W1 = (const float*)d_in[2];
    const float* b1 = (const float*)d_in[3];
    const float* W2 = (const float*)d_in[4];
    const float* b2 = (const float*)d_in[5];
    float* out = (float*)d_out;

    const int N = in_sizes[0] / 512;   // 100000
    const int E = in_sizes[1] / 2;     // 1600000
    const int* src = ei;
    const int* dst = ei + E;

    const int NBUCKET = (N + 255) >> BSHIFT;      // 391
    const int NB_E    = (E + EB - 1) / EB;        // 391
    const int T       = NBUCKET * NB_E;           // 152881
    const int nbb     = (T + 255) / 256;          // 598 <= 1024

    // workspace layout
    char* ws = (char*)d_ws;
    size_t o = 0;
    auto take = [&](size_t bytes) { char* p = ws + o; o = (o + bytes + 255) & ~(size_t)255; return p; };
    int*            cnt       = (int*)take((size_t)N * 4);
    int*            bsum      = (int*)take(1024 * 4);
    int*            row_start = (int*)take((size_t)N * 4);
    float*          dinv      = (float*)take((size_t)N * 4);
    int*            srcs      = (int*)take((size_t)E * 4);
    uint2*          ebuf      = (uint2*)take((size_t)E * 8);
    int*            counts    = (int*)take((size_t)T * 4);
    int*            offs      = (int*)take((size_t)T * 4);
    __hip_bfloat16* W1t       = (__hip_bfloat16*)take((size_t)128 * 512 * 2);
    __hip_bfloat16* W2t       = (__hip_bfloat16*)take((size_t)64 * 128 * 2);
    __hip_bfloat16* h         = (__hip_bfloat16*)take((size_t)N * 128 * 2);   // h' = dinv*h
    __hip_bfloat16* r         = (__hip_bfloat16*)take((size_t)N * 128 * 2);
    __hip_bfloat16* h2        = (__hip_bfloat16*)take((size_t)N * 64 * 2);    // h2' = dinv*h2

    const int mb = (N + 127) / 128;

    // ---- CSR build via bucketed counting sort (no global atomics) ----
    hist_bucket<<<NB_E, 256, 0, stream>>>(dst, counts, NB_E, NBUCKET, E);
    scan_block_sums<<<nbb, 256, 0, stream>>>(counts, bsum, T);
    scan_bsums<<<1, 1024, 0, stream>>>(bsum, nbb);
    scan_offs<<<nbb, 256, 0, stream>>>(counts, bsum, offs, T);
    scatter_bucketed<<<NB_E, 256, 0, stream>>>(src, dst, offs, ebuf, NB_E, NBUCKET, E);
    bucket_csr<<<NBUCKET, 256, 0, stream>>>(ebuf, offs, row_start, cnt, dinv, srcs,
                                            NB_E, NBUCKET, N, E);

    // weights
    conv_w1t<<<(128 * 512) / 256, 256, 0, stream>>>(W1, W1t);
    conv_w2t<<<(64 * 128) / 256, 256, 0, stream>>>(W2, W2t);

    // layer 1
    gemm1_mfma<<<mb, 256, 0, stream>>>(x, W1t, dinv, h, N);
    agg1_gather4<<<(N + 3) / 4, 256, 0, stream>>>(row_start, cnt, srcs, dinv,
                                                  (const uint4*)h, b1, (uint4*)r, N);

    // layer 2
    gemm2_mfma<<<mb, 256, 0, stream>>>(r, W2t, dinv, h2, N);
    agg2_lsm4<<<(N + 3) / 4, 256, 0, stream>>>(row_start, cnt, srcs, dinv,
                                               (const uint2*)h2, b2, out, N);
}

// Round 6
// 246.010 us; speedup vs baseline: 6.1170x; 1.1258x over previous
//
#include <hip/hip_runtime.h>
#include <hip/hip_bf16.h>

// ---------------------------------------------------------------------------
// GCN 2-layer forward. Bucketed CSR + MFMA GEMM1 + fused agg1+relu+GEMM2:
//   h'  = dinv * (x @ W1)   (bf16)
//   agg1_fused: r = relu(di*(h'[n]+sum h'[src])+b1) -> LDS -> h2' = dinv*(r@W2)
//   agg2_lsm: out = log_softmax(di*(h2'[n]+sum h2'[src])+b2)
// ---------------------------------------------------------------------------

typedef float f32x4 __attribute__((ext_vector_type(4)));
typedef short bf16x8 __attribute__((ext_vector_type(8)));

__device__ inline float bf16_lo(unsigned int p) {
    return __uint_as_float((p & 0xffffu) << 16);
}
__device__ inline float bf16_hi(unsigned int p) {
    return __uint_as_float(p & 0xffff0000u);
}
__device__ inline unsigned short bf16_bits(float f) {
    __hip_bfloat16 b = __float2bfloat16(f);
    return *reinterpret_cast<unsigned short*>(&b);
}
__device__ inline unsigned int pack_bf16(float a, float b) {
    return (unsigned int)bf16_bits(a) | ((unsigned int)bf16_bits(b) << 16);
}

#define EB 4096            // edges per block in bucketing passes
#define BSHIFT 8           // bucket = dst >> 8

// ---------------- pass 1: per-(block,bucket) histogram ----------------
__global__ __launch_bounds__(256) void hist_bucket(const int* __restrict__ dst,
                                                   int* __restrict__ counts,   // [NBUCKET][NB_E]
                                                   int NB_E, int NBUCKET, int E) {
    __shared__ int hist[512];
    const int tid = threadIdx.x;
    for (int i = tid; i < NBUCKET; i += 256) hist[i] = 0;
    __syncthreads();
    const int e0 = blockIdx.x * EB;
    const int e1 = min(e0 + EB, E);
    for (int e = e0 + tid; e < e1; e += 256)
        atomicAdd(&hist[dst[e] >> BSHIFT], 1);
    __syncthreads();
    for (int i = tid; i < NBUCKET; i += 256)
        counts[(size_t)i * NB_E + blockIdx.x] = hist[i];
}

// ---------------- scan machinery (2-level, exclusive) ----------------
__global__ __launch_bounds__(256) void scan_block_sums(const int* __restrict__ v, int* __restrict__ bsum, int T) {
    __shared__ int s[256];
    int i = blockIdx.x * 256 + threadIdx.x;
    s[threadIdx.x] = (i < T) ? v[i] : 0;
    __syncthreads();
    for (int off = 128; off > 0; off >>= 1) {
        if (threadIdx.x < off) s[threadIdx.x] += s[threadIdx.x + off];
        __syncthreads();
    }
    if (threadIdx.x == 0) bsum[blockIdx.x] = s[0];
}

__global__ __launch_bounds__(1024) void scan_bsums(int* bsum, int nb) {
    __shared__ int s[1024];
    int v = (threadIdx.x < nb) ? bsum[threadIdx.x] : 0;
    s[threadIdx.x] = v;
    __syncthreads();
    for (int off = 1; off < 1024; off <<= 1) {
        int t = (threadIdx.x >= off) ? s[threadIdx.x - off] : 0;
        __syncthreads();
        s[threadIdx.x] += t;
        __syncthreads();
    }
    if (threadIdx.x < nb) bsum[threadIdx.x] = s[threadIdx.x] - v;  // exclusive
}

__global__ __launch_bounds__(256) void scan_offs(const int* __restrict__ v, const int* __restrict__ bsum,
                                                 int* __restrict__ offs, int T) {
    __shared__ int s[256];
    int i = blockIdx.x * 256 + threadIdx.x;
    int x = (i < T) ? v[i] : 0;
    s[threadIdx.x] = x;
    __syncthreads();
    for (int off = 1; off < 256; off <<= 1) {
        int t = (threadIdx.x >= off) ? s[threadIdx.x - off] : 0;
        __syncthreads();
        s[threadIdx.x] += t;
        __syncthreads();
    }
    if (i < T) offs[i] = s[threadIdx.x] - x + bsum[blockIdx.x];
}

// ------ pass 3: bucket-major edge materialization (packed 4B records) ------
// record = src (bits 0..23) | local_dst (bits 24..31)
__global__ __launch_bounds__(256) void scatter_bucketed(const int* __restrict__ src,
                                                        const int* __restrict__ dst,
                                                        const int* __restrict__ offs,  // [NBUCKET][NB_E]
                                                        unsigned* __restrict__ ebuf,
                                                        int NB_E, int NBUCKET, int E) {
    __shared__ int lcur[512];
    const int tid = threadIdx.x;
    for (int i = tid; i < NBUCKET; i += 256)
        lcur[i] = offs[(size_t)i * NB_E + blockIdx.x];
    __syncthreads();
    const int e0 = blockIdx.x * EB;
    const int e1 = min(e0 + EB, E);
    for (int e = e0 + tid; e < e1; e += 256) {
        const int d = dst[e];
        const int s = src[e];
        const int pos = atomicAdd(&lcur[d >> BSHIFT], 1);
        ebuf[pos] = (unsigned)s | ((unsigned)(d & 255) << 24);
    }
}

// ---------------- pass 4: per-bucket CSR finalize (all LDS) ----------------
__global__ __launch_bounds__(256) void bucket_csr(const unsigned* __restrict__ ebuf,
                                                  const int* __restrict__ offs,
                                                  int* __restrict__ row_start,
                                                  int* __restrict__ cnt,
                                                  float* __restrict__ dinv,
                                                  int* __restrict__ srcs,
                                                  int NB_E, int NBUCKET, int N, int E) {
    __shared__ int lcnt[256];
    __shared__ int lscan[256];
    __shared__ int lcur[256];
    const int tid = threadIdx.x;
    const int b = blockIdx.x;
    const int node_base = b << BSHIFT;
    const int ebeg = offs[(size_t)b * NB_E];
    const int eend = (b + 1 < NBUCKET) ? offs[(size_t)(b + 1) * NB_E] : E;

    lcnt[tid] = 0;
    __syncthreads();
    for (int e = ebeg + tid; e < eend; e += 256)
        atomicAdd(&lcnt[ebuf[e] >> 24], 1);
    __syncthreads();

    // exclusive scan of lcnt
    int v = lcnt[tid];
    lscan[tid] = v;
    __syncthreads();
    for (int off = 1; off < 256; off <<= 1) {
        int t = (tid >= off) ? lscan[tid - off] : 0;
        __syncthreads();
        lscan[tid] += t;
        __syncthreads();
    }
    const int excl = lscan[tid] - v;

    const int node = node_base + tid;
    if (node < N) {
        row_start[node] = ebeg + excl;
        cnt[node]       = v;
        dinv[node]      = rsqrtf((float)(v + 1));
    }
    lcur[tid] = excl;
    __syncthreads();

    for (int e = ebeg + tid; e < eend; e += 256) {
        const unsigned p = ebuf[e];
        const int pos = ebeg + atomicAdd(&lcur[p >> 24], 1);
        srcs[pos] = (int)(p & 0xFFFFFFu);
    }
}

// ---------------- weight transpose + bf16 convert ----------------
__global__ __launch_bounds__(256) void conv_w1t(const float* __restrict__ W1, __hip_bfloat16* __restrict__ W1t) {
    int idx = blockIdx.x * 256 + threadIdx.x;      // 128*512
    int c = idx >> 9, k = idx & 511;
    W1t[idx] = __float2bfloat16(W1[k * 128 + c]);
}
__global__ __launch_bounds__(256) void conv_w2t(const float* __restrict__ W2, __hip_bfloat16* __restrict__ W2t) {
    int idx = blockIdx.x * 256 + threadIdx.x;      // 64*128
    int c = idx >> 7, k = idx & 127;
    W2t[idx] = __float2bfloat16(W2[k * 64 + c]);
}

// ---------------- GEMM1: h' = dinv * (x @ W1)  (MFMA bf16) ----------------
__global__ __launch_bounds__(256) void gemm1_mfma(const float* __restrict__ A,          // [M][512]
                                                  const __hip_bfloat16* __restrict__ Bt, // [128][512]
                                                  const float* __restrict__ dinv,
                                                  __hip_bfloat16* __restrict__ C,        // [M][128]
                                                  int M) {
    __shared__ __hip_bfloat16 As[128 * 64];
    __shared__ __hip_bfloat16 Bs[128 * 64];
    __shared__ float sdinv[128];
    const int tid  = threadIdx.x;
    const int lane = tid & 63;
    const int wid  = tid >> 6;
    const int wr   = wid >> 1, wc = wid & 1;
    const int g    = lane >> 4, l15 = lane & 15;
    const int row0 = blockIdx.x * 128;

    if (tid < 128) {
        int gr = row0 + tid;
        sdinv[tid] = dinv[gr < M ? gr : M - 1];
    }

    f32x4 acc[4][4] = {};

    for (int kt = 0; kt < 8; ++kt) {
        #pragma unroll
        for (int it = 0; it < 8; ++it) {
            const int r = it * 16 + (tid >> 4);
            const int k = (tid & 15) * 4;
            int gr = row0 + r; if (gr >= M) gr = M - 1;
            const f32x4 v = *reinterpret_cast<const f32x4*>(A + (size_t)gr * 512 + kt * 64 + k);
            ushort4 p;
            p.x = bf16_bits(v.x); p.y = bf16_bits(v.y);
            p.z = bf16_bits(v.z); p.w = bf16_bits(v.w);
            const int kw = k ^ ((r & 7) << 3);
            *reinterpret_cast<ushort4*>(&As[r * 64 + kw]) = p;
        }
        #pragma unroll
        for (int it = 0; it < 4; ++it) {
            const int c = it * 32 + (tid >> 3);
            const int k = (tid & 7) * 8;
            const uint4 v = *reinterpret_cast<const uint4*>(Bt + (size_t)c * 512 + kt * 64 + k);
            const int kw = k ^ ((c & 7) << 3);
            *reinterpret_cast<uint4*>(&Bs[c * 64 + kw]) = v;
        }
        __syncthreads();
        #pragma unroll
        for (int kk = 0; kk < 2; ++kk) {
            bf16x8 af[4], bfr[4];
            const int k0 = kk * 32 + g * 8;
            #pragma unroll
            for (int i = 0; i < 4; ++i) {
                const int r = wr * 64 + i * 16 + l15;
                af[i] = *reinterpret_cast<const bf16x8*>(&As[r * 64 + (k0 ^ ((r & 7) << 3))]);
            }
            #pragma unroll
            for (int j = 0; j < 4; ++j) {
                const int c = wc * 64 + j * 16 + l15;
                bfr[j] = *reinterpret_cast<const bf16x8*>(&Bs[c * 64 + (k0 ^ ((c & 7) << 3))]);
            }
            #pragma unroll
            for (int i = 0; i < 4; ++i)
                #pragma unroll
                for (int j = 0; j < 4; ++j)
                    acc[i][j] = __builtin_amdgcn_mfma_f32_16x16x32_bf16(af[i], bfr[j], acc[i][j], 0, 0, 0);
        }
        __syncthreads();
    }
    #pragma unroll
    for (int i = 0; i < 4; ++i) {
        #pragma unroll
        for (int q = 0; q < 4; ++q) {
            const int lr  = wr * 64 + i * 16 + g * 4 + q;
            const int row = row0 + lr;
            if (row < M) {
                const float dv = sdinv[lr];
                #pragma unroll
                for (int j = 0; j < 4; ++j)
                    C[(size_t)row * 128 + wc * 64 + j * 16 + l15] = __float2bfloat16(acc[i][j][q] * dv);
            }
        }
    }
}

// ---- fused agg1 + bias + relu + (r @ W2) + dinv scale -> h2' (bf16) ------
// Block: 256 thr = 4 waves = 4 nodes. Gather: 4 slots x 16 lanes, unroll 2
// (8 rows in flight/wave). Then r rows -> LDS (bf16, XOR swizzle) and a
// 16x16x128 mini-MFMA per wave (rows 4..15 garbage, discarded).
__global__ __launch_bounds__(256) void agg1_fused(const int* __restrict__ row_start,
                                                  const int* __restrict__ cnt,
                                                  const int* __restrict__ srcs,
                                                  const float* __restrict__ dinv,
                                                  const uint4* __restrict__ h4,   // [N][16] (128 bf16)
                                                  const float* __restrict__ b1,
                                                  const __hip_bfloat16* __restrict__ W2t, // [64][128]
                                                  __hip_bfloat16* __restrict__ h2,        // [N][64]
                                                  int N) {
    __shared__ __hip_bfloat16 w2s[64 * 128];   // 16 KB, swizzled
    __shared__ __hip_bfloat16 rs[16 * 128];    // 4 KB, rows 0..3 valid
    const int tid  = threadIdx.x;
    const int w    = tid >> 6;
    const int lane = tid & 63;
    const int s    = lane >> 4, li = lane & 15;

    // stage W2t into LDS with gemm-style swizzle: (c,k) -> c*128 + (k^((c&15)<<3))
    {
        const uint4* s4 = reinterpret_cast<const uint4*>(W2t);
        for (int i = tid; i < 1024; i += 256) {
            const int c = i >> 4;
            const int k = (i & 15) * 8;
            const uint4 v = s4[i];
            *reinterpret_cast<uint4*>(&w2s[c * 128 + (k ^ ((c & 15) << 3))]) = v;
        }
    }

    const int node = blockIdx.x * 4 + w;
    const bool active = node < N;

    float acc[8] = {};
    int beg = 0, num = 0;
    if (active) { beg = row_start[node]; num = cnt[node]; }
    if (active && s == 0) {   // self-loop term once
        uint4 v = h4[(size_t)node * 16 + li];
        acc[0] += bf16_lo(v.x); acc[1] += bf16_hi(v.x);
        acc[2] += bf16_lo(v.y); acc[3] += bf16_hi(v.y);
        acc[4] += bf16_lo(v.z); acc[5] += bf16_hi(v.z);
        acc[6] += bf16_lo(v.w); acc[7] += bf16_hi(v.w);
    }
    int j = 0;
    for (; j + 8 <= num; j += 8) {
        const int sn0 = srcs[beg + j + s];
        const int sn1 = srcs[beg + j + 4 + s];
        const uint4 v0 = h4[(size_t)sn0 * 16 + li];
        const uint4 v1 = h4[(size_t)sn1 * 16 + li];
        acc[0] += bf16_lo(v0.x); acc[1] += bf16_hi(v0.x);
        acc[2] += bf16_lo(v0.y); acc[3] += bf16_hi(v0.y);
        acc[4] += bf16_lo(v0.z); acc[5] += bf16_hi(v0.z);
        acc[6] += bf16_lo(v0.w); acc[7] += bf16_hi(v0.w);
        acc[0] += bf16_lo(v1.x); acc[1] += bf16_hi(v1.x);
        acc[2] += bf16_lo(v1.y); acc[3] += bf16_hi(v1.y);
        acc[4] += bf16_lo(v1.z); acc[5] += bf16_hi(v1.z);
        acc[6] += bf16_lo(v1.w); acc[7] += bf16_hi(v1.w);
    }
    if (j + s < num) {
        const int sn = srcs[beg + j + s];
        const uint4 v = h4[(size_t)sn * 16 + li];
        acc[0] += bf16_lo(v.x); acc[1] += bf16_hi(v.x);
        acc[2] += bf16_lo(v.y); acc[3] += bf16_hi(v.y);
        acc[4] += bf16_lo(v.z); acc[5] += bf16_hi(v.z);
        acc[6] += bf16_lo(v.w); acc[7] += bf16_hi(v.w);
    }
    if (j + 4 + s < num) {
        const int sn = srcs[beg + j + 4 + s];
        const uint4 v = h4[(size_t)sn * 16 + li];
        acc[0] += bf16_lo(v.x); acc[1] += bf16_hi(v.x);
        acc[2] += bf16_lo(v.y); acc[3] += bf16_hi(v.y);
        acc[4] += bf16_lo(v.z); acc[5] += bf16_hi(v.z);
        acc[6] += bf16_lo(v.w); acc[7] += bf16_hi(v.w);
    }
    #pragma unroll
    for (int t = 0; t < 8; ++t) {
        acc[t] += __shfl_xor(acc[t], 16);
        acc[t] += __shfl_xor(acc[t], 32);
    }
    if (active && s == 0) {
        const float di = dinv[node];
        const float4 bb0 = reinterpret_cast<const float4*>(b1)[li * 2];
        const float4 bb1 = reinterpret_cast<const float4*>(b1)[li * 2 + 1];
        const float r0 = fmaxf(fmaf(di, acc[0], bb0.x), 0.0f);
        const float r1 = fmaxf(fmaf(di, acc[1], bb0.y), 0.0f);
        const float r2 = fmaxf(fmaf(di, acc[2], bb0.z), 0.0f);
        const float r3 = fmaxf(fmaf(di, acc[3], bb0.w), 0.0f);
        const float r4 = fmaxf(fmaf(di, acc[4], bb1.x), 0.0f);
        const float r5 = fmaxf(fmaf(di, acc[5], bb1.y), 0.0f);
        const float r6 = fmaxf(fmaf(di, acc[6], bb1.z), 0.0f);
        const float r7 = fmaxf(fmaf(di, acc[7], bb1.w), 0.0f);
        uint4 o;
        o.x = pack_bf16(r0, r1); o.y = pack_bf16(r2, r3);
        o.z = pack_bf16(r4, r5); o.w = pack_bf16(r6, r7);
        const int k = li * 8;
        *reinterpret_cast<uint4*>(&rs[w * 128 + (k ^ ((w & 15) << 3))]) = o;
    }
    __syncthreads();   // uniform: no early returns above

    // mini-GEMM: C[row 0..3][w*16 .. w*16+15], K=128
    f32x4 oacc = {};
    #pragma unroll
    for (int kk = 0; kk < 4; ++kk) {
        const int k0 = kk * 32 + s * 8;
        const bf16x8 af = *reinterpret_cast<const bf16x8*>(&rs[li * 128 + (k0 ^ ((li & 15) << 3))]);
        const int c = w * 16 + li;
        const bf16x8 bfr = *reinterpret_cast<const bf16x8*>(&w2s[c * 128 + (k0 ^ ((c & 15) << 3))]);
        oacc = __builtin_amdgcn_mfma_f32_16x16x32_bf16(af, bfr, oacc, 0, 0, 0);
    }
    if (s == 0) {      // D rows g*4+q; only g==0 holds rows 0..3
        #pragma unroll
        for (int q = 0; q < 4; ++q) {
            const int nd = blockIdx.x * 4 + q;
            if (nd < N) {
                const float dv = dinv[nd];
                h2[(size_t)nd * 64 + w * 16 + li] = __float2bfloat16(oacc[q] * dv);
            }
        }
    }
}

// ------- layer-2 aggregation + bias + log_softmax, 4 slots, unroll 2 -------
__global__ __launch_bounds__(256) void agg2_lsm4(const int* __restrict__ row_start,
                                                 const int* __restrict__ cnt,
                                                 const int* __restrict__ srcs,
                                                 const float* __restrict__ dinv,
                                                 const uint2* __restrict__ h2v,  // [N][16] (64 bf16)
                                                 const float* __restrict__ b2,
                                                 float* __restrict__ out, int N) {
    int node = blockIdx.x * 4 + (threadIdx.x >> 6);
    if (node >= N) return;
    const int lane = threadIdx.x & 63;
    const int s = lane >> 4, li = lane & 15;

    float acc[4] = {};
    if (s == 0) {
        uint2 v = h2v[(size_t)node * 16 + li];
        acc[0] += bf16_lo(v.x); acc[1] += bf16_hi(v.x);
        acc[2] += bf16_lo(v.y); acc[3] += bf16_hi(v.y);
    }
    const int beg = row_start[node];
    const int num = cnt[node];
    int j = 0;
    for (; j + 8 <= num; j += 8) {
        const int sn0 = srcs[beg + j + s];
        const int sn1 = srcs[beg + j + 4 + s];
        const uint2 v0 = h2v[(size_t)sn0 * 16 + li];
        const uint2 v1 = h2v[(size_t)sn1 * 16 + li];
        acc[0] += bf16_lo(v0.x); acc[1] += bf16_hi(v0.x);
        acc[2] += bf16_lo(v0.y); acc[3] += bf16_hi(v0.y);
        acc[0] += bf16_lo(v1.x); acc[1] += bf16_hi(v1.x);
        acc[2] += bf16_lo(v1.y); acc[3] += bf16_hi(v1.y);
    }
    if (j + s < num) {
        const int sn = srcs[beg + j + s];
        const uint2 v = h2v[(size_t)sn * 16 + li];
        acc[0] += bf16_lo(v.x); acc[1] += bf16_hi(v.x);
        acc[2] += bf16_lo(v.y); acc[3] += bf16_hi(v.y);
    }
    if (j + 4 + s < num) {
        const int sn = srcs[beg + j + 4 + s];
        const uint2 v = h2v[(size_t)sn * 16 + li];
        acc[0] += bf16_lo(v.x); acc[1] += bf16_hi(v.x);
        acc[2] += bf16_lo(v.y); acc[3] += bf16_hi(v.y);
    }
    #pragma unroll
    for (int t = 0; t < 4; ++t) {
        acc[t] += __shfl_xor(acc[t], 16);
        acc[t] += __shfl_xor(acc[t], 32);
    }
    const float di = dinv[node];
    const float4 bb = reinterpret_cast<const float4*>(b2)[li];
    float v0 = fmaf(di, acc[0], bb.x);
    float v1 = fmaf(di, acc[1], bb.y);
    float v2 = fmaf(di, acc[2], bb.z);
    float v3 = fmaf(di, acc[3], bb.w);
    float m = fmaxf(fmaxf(v0, v1), fmaxf(v2, v3));
    #pragma unroll
    for (int o = 8; o > 0; o >>= 1) m = fmaxf(m, __shfl_xor(m, o));
    float es = expf(v0 - m) + expf(v1 - m) + expf(v2 - m) + expf(v3 - m);
    #pragma unroll
    for (int o = 8; o > 0; o >>= 1) es += __shfl_xor(es, o);
    if (s == 0) {
        const float lse = m + logf(es);
        float4 r;
        r.x = v0 - lse; r.y = v1 - lse; r.z = v2 - lse; r.w = v3 - lse;
        reinterpret_cast<float4*>(out)[(size_t)node * 16 + li] = r;
    }
}

// ---------------------------------------------------------------------------
extern "C" void kernel_launch(void* const* d_in, const int* in_sizes, int n_in,
                              void* d_out, int out_size, void* d_ws, size_t ws_size,
                              hipStream_t stream) {
    const float* x  = (const float*)d_in[0];
    const int*   ei = (const int*)d_in[1];
    const float* W1 = (const float*)d_in[2];
    const float* b1 = (const float*)d_in[3];
    const float* W2 = (const float*)d_in[4];
    const float* b2 = (const float*)d_in[5];
    float* out = (float*)d_out;

    const int N = in_sizes[0] / 512;   // 100000
    const int E = in_sizes[1] / 2;     // 1600000
    const int* src = ei;
    const int* dst = ei + E;

    const int NBUCKET = (N + 255) >> BSHIFT;      // 391
    const int NB_E    = (E + EB - 1) / EB;        // 391
    const int T       = NBUCKET * NB_E;           // 152881
    const int nbb     = (T + 255) / 256;          // 598 <= 1024

    // workspace layout
    char* ws = (char*)d_ws;
    size_t o = 0;
    auto take = [&](size_t bytes) { char* p = ws + o; o = (o + bytes + 255) & ~(size_t)255; return p; };
    int*            cnt       = (int*)take((size_t)N * 4);
    int*            bsum      = (int*)take(1024 * 4);
    int*            row_start = (int*)take((size_t)N * 4);
    float*          dinv      = (float*)take((size_t)N * 4);
    int*            srcs      = (int*)take((size_t)E * 4);
    unsigned*       ebuf      = (unsigned*)take((size_t)E * 4);
    int*            counts    = (int*)take((size_t)T * 4);
    int*            offs      = (int*)take((size_t)T * 4);
    __hip_bfloat16* W1t       = (__hip_bfloat16*)take((size_t)128 * 512 * 2);
    __hip_bfloat16* W2t       = (__hip_bfloat16*)take((size_t)64 * 128 * 2);
    __hip_bfloat16* h         = (__hip_bfloat16*)take((size_t)N * 128 * 2);   // h' = dinv*h
    __hip_bfloat16* h2        = (__hip_bfloat16*)take((size_t)N * 64 * 2);    // h2' = dinv*h2

    const int mb = (N + 127) / 128;

    // ---- CSR build via bucketed counting sort (no global atomics) ----
    hist_bucket<<<NB_E, 256, 0, stream>>>(dst, counts, NB_E, NBUCKET, E);
    scan_block_sums<<<nbb, 256, 0, stream>>>(counts, bsum, T);
    scan_bsums<<<1, 1024, 0, stream>>>(bsum, nbb);
    scan_offs<<<nbb, 256, 0, stream>>>(counts, bsum, offs, T);
    scatter_bucketed<<<NB_E, 256, 0, stream>>>(src, dst, offs, ebuf, NB_E, NBUCKET, E);
    bucket_csr<<<NBUCKET, 256, 0, stream>>>(ebuf, offs, row_start, cnt, dinv, srcs,
                                            NB_E, NBUCKET, N, E);

    // weights
    conv_w1t<<<(128 * 512) / 256, 256, 0, stream>>>(W1, W1t);
    conv_w2t<<<(64 * 128) / 256, 256, 0, stream>>>(W2, W2t);

    // layer 1 + fused layer-2 transform
    gemm1_mfma<<<mb, 256, 0, stream>>>(x, W1t, dinv, h, N);
    agg1_fused<<<(N + 3) / 4, 256, 0, stream>>>(row_start, cnt, srcs, dinv,
                                                (const uint4*)h, b1, W2t, h2, N);

    // layer-2 aggregation + log_softmax
    agg2_lsm4<<<(N + 3) / 4, 256, 0, stream>>>(row_start, cnt, srcs, dinv,
                                               (const uint2*)h2, b2, out, N);
}